// Round 18
// baseline (295.479 us; speedup 1.0000x reference)
//
#include <hip/hip_runtime.h>

typedef unsigned int   u32;
typedef unsigned short u16;

typedef float  f32x4  __attribute__((ext_vector_type(4)));
typedef u32    u32x4  __attribute__((ext_vector_type(4)));
typedef u16    u16x4  __attribute__((ext_vector_type(4)));
typedef __bf16 bf16x8 __attribute__((ext_vector_type(8)));

union FragU { u16 us[8]; u32x4 q; bf16x8 v; };

__device__ __forceinline__ u32 f2u(float x){ union{float f;u32 u;}c; c.f=x; return c.u; }
__device__ __forceinline__ float u2f(u32 u){ union{float f;u32 u;}c; c.u=u; return c.f; }
__device__ __forceinline__ u16 bfhi(float x){ u32 u=f2u(x); return (u16)((u + 0x7fffu + ((u>>16)&1u))>>16); }
// pack two fp32 -> (bf16(a) | bf16(b)<<16) via HW cvt (RNE, matches bfhi)
__device__ __forceinline__ u32 cvtpk(float a, float b){
  u32 r;
  asm("v_cvt_pk_bf16_f32 %0, %1, %2" : "=v"(r) : "v"(a), "v"(b));
  return r;
}

__device__ __forceinline__ void gload16(const void* g, void* l){
  __builtin_amdgcn_global_load_lds(
      (const __attribute__((address_space(1))) unsigned int*)g,
      (__attribute__((address_space(3))) unsigned int*)l, 16, 0, 0);
}

// ---------------------------------------------------------------------------
// Fused prep: fp32->bf16 packing of 3 buffers (blocks 0..1535; 4-way unrolled
// grid-stride, 8 loads in flight per thread) + paged-cache gather
// (blocks 1536..2559).  n* counted in groups of 8 floats; totals hit 16
// groups per thread exactly.
// ---------------------------------------------------------------------------
__global__ __launch_bounds__(256)
void prep_all(const float* __restrict__ s0, u32* __restrict__ d0, int n0,
              const float* __restrict__ s1, u32* __restrict__ d1, int n1,
              const float* __restrict__ s2, u32* __restrict__ d2, int n2,
              const float* __restrict__ k_cache, const float* __restrict__ v_cache,
              const int* __restrict__ page_table,
              u16* __restrict__ k_all, u16* __restrict__ v_allT)
{
  const int tid = threadIdx.x;
  if (blockIdx.x < 1536){
    const int total = n0 + n1 + n2;      // 8-float groups (= 6291456)
    const int S = 1536*256;
    for (int i0 = blockIdx.x*256 + tid; i0 < total; i0 += 4*S){
      f32x4 a[4], bql[4]; u32* dp[4]; int jj[4]; bool ok[4];
      #pragma unroll
      for (int u=0;u<4;u++){
        int j = i0 + u*S;
        ok[u] = (j < total);
        const float* s; u32* d;
        if (j < n0)            { s = s0; d = d0; }
        else if (j < n0 + n1)  { s = s1; d = d1; j -= n0; }
        else                   { s = s2; d = d2; j -= n0 + n1; }
        if (ok[u]){
          a[u]   = __builtin_nontemporal_load(reinterpret_cast<const f32x4*>(s) + 2*j);
          bql[u] = __builtin_nontemporal_load(reinterpret_cast<const f32x4*>(s) + 2*j + 1);
        }
        dp[u] = d; jj[u] = j;
      }
      #pragma unroll
      for (int u=0;u<4;u++){
        if (ok[u])
          reinterpret_cast<u32x4*>(dp[u])[jj[u]] =
            (u32x4){ cvtpk(a[u].x,a[u].y), cvtpk(a[u].z,a[u].w),
                     cvtpk(bql[u].x,bql[u].y), cvtpk(bql[u].z,bql[u].w) };
      }
    }
    return;
  }
  __shared__ float tb[32][129];
  const int id = blockIdx.x - 1536;
  const int jt = id & 31, h = (id>>5)&7, b = id>>8;
  const int j0 = jt*32;
  {
    int r = tid>>3, c = tid&7;           // row 0..31, 8 chunks
    int j = j0 + r;
    int page = page_table[b*64 + (j>>4)];
    int slot = j & 15;
    const float* ks = k_cache + (size_t)((page*16 + slot)*8 + h)*128;
    const float* vs = v_cache + (size_t)((page*16 + slot)*8 + h)*128;
    u16* kd = k_all + ((size_t)(b*8+h)*1024 + j)*128;
    #pragma unroll
    for (int i=0;i<2;i++){
      int d0i = (c + 8*i)*8;             // 8 d-elems per iter
      f32x4 ka = __builtin_nontemporal_load(reinterpret_cast<const f32x4*>(ks + d0i));
      f32x4 kb = __builtin_nontemporal_load(reinterpret_cast<const f32x4*>(ks + d0i + 4));
      *reinterpret_cast<u32x4*>(kd + d0i) =
        (u32x4){ cvtpk(ka.x,ka.y), cvtpk(ka.z,ka.w), cvtpk(kb.x,kb.y), cvtpk(kb.z,kb.w) };
      f32x4 va = __builtin_nontemporal_load(reinterpret_cast<const f32x4*>(vs + d0i));
      f32x4 vb = __builtin_nontemporal_load(reinterpret_cast<const f32x4*>(vs + d0i + 4));
      tb[r][d0i+0]=va.x; tb[r][d0i+1]=va.y; tb[r][d0i+2]=va.z; tb[r][d0i+3]=va.w;
      tb[r][d0i+4]=vb.x; tb[r][d0i+5]=vb.y; tb[r][d0i+6]=vb.z; tb[r][d0i+7]=vb.w;
    }
  }
  __syncthreads();
  {
    int dout = tid>>1, jh = tid&1;       // d-row 0..127, j-half 0..1
    u16* vd = v_allT + ((size_t)(b*8+h)*128 + dout)*1024 + j0 + jh*16;
    #pragma unroll
    for (int i=0;i<2;i++){
      int jb = jh*16 + i*8;
      u32x4 o = { cvtpk(tb[jb+0][dout], tb[jb+1][dout]),
                  cvtpk(tb[jb+2][dout], tb[jb+3][dout]),
                  cvtpk(tb[jb+4][dout], tb[jb+5][dout]),
                  cvtpk(tb[jb+6][dout], tb[jb+7][dout]) };
      *reinterpret_cast<u32x4*>(vd + i*8) = o;
    }
  }
}

// ---------------------------------------------------------------------------
// 128x192-tile GEMM on bf16 (grid 512 = 2 blocks/CU).
// 4 waves (2Mx2N), wave tile 64x96, BK=64 bf16, dbuf 80KB LDS,
// 2 fat phases/K-tile, counted vmcnt(6), both-sides swizzle, setprio.
// ---------------------------------------------------------------------------
__global__ __launch_bounds__(256, 2)
void gemm_pkA2(const u16* __restrict__ A, const u16* __restrict__ B,
               float* __restrict__ C, int M, int N, int K)  // K = bf16 per row
{
  extern __shared__ char smem[];   // 81920 B: [buf2][ A 16KB | B 24KB ]
  const int tid  = threadIdx.x;
  const int lane = tid & 63;
  const int w    = tid >> 6;       // 0..3
  const int wm = w >> 1, wn = w & 1;
  const int ln = lane & 15, lg = lane >> 4;

  const int nbm = M >> 7;          // 128-row tiles
  const int nbn = N / 192;
  const int nwg = nbm * nbn;
  const int swz = (blockIdx.x & 7) * (nwg >> 3) + (blockIdx.x >> 3);
  const int bm = swz % nbm, bn = swz / nbm;

  const size_t rb = (size_t)K * 2;           // row bytes
  const int lrow  = lane >> 3;               // 0..7
  const int lslot = (lane & 7) ^ (lrow & 7); // pre-swizzled source slot
  const char* As0 = (const char*)A + (size_t)(bm*128 + w*8 + lrow)*rb + lslot*16;
  const char* Bs0 = (const char*)B + (size_t)(bn*192 + w*8 + lrow)*rb + lslot*16;

  auto stA = [&](int buf, int t) {           // 4 issues: 128 rows
    const char* s = As0 + ((size_t)t << 7);
    char* d = smem + buf*40960 + w*1024;
    gload16(s,           d);
    gload16(s +  32*rb,  d + 4096);
    gload16(s +  64*rb,  d + 8192);
    gload16(s +  96*rb,  d + 12288);
  };
  auto stB = [&](int buf, int t) {           // 6 issues: 192 rows
    const char* s = Bs0 + ((size_t)t << 7);
    char* d = smem + buf*40960 + 16384 + w*1024;
    gload16(s,           d);
    gload16(s +  32*rb,  d + 4096);
    gload16(s +  64*rb,  d + 8192);
    gload16(s +  96*rb,  d + 12288);
    gload16(s + 128*rb,  d + 16384);
    gload16(s + 160*rb,  d + 20480);
  };

  f32x4 z = {0.f,0.f,0.f,0.f};
  f32x4 acc[4][6];
  #pragma unroll
  for (int i=0;i<4;i++){
    #pragma unroll
    for (int j=0;j<6;j++) acc[i][j] = z;
  }

  const int nt = K >> 6;           // K-tiles of 64 bf16
  stA(0, 0); stB(0, 0);            // 10 loads
  if (nt > 1) { stB(1, 1);         // +6
    asm volatile("s_waitcnt vmcnt(6)" ::: "memory");   // tile0's 10 complete
  } else {
    asm volatile("s_waitcnt vmcnt(0)" ::: "memory");
  }
  __builtin_amdgcn_s_barrier();
  asm volatile("" ::: "memory");

  const int lx7 = ln & 7;

  for (int t = 0; t < nt; ++t){
    const int cur = t & 1;
    const char* bufc = smem + cur*40960;

    // ---- phase 0: all B frags + A m-frags 0..1; stage A(t+1) ----
    FragU bfr[6][2];
    #pragma unroll
    for (int ni=0; ni<6; ni++){
      const int rofs = 16384 + (wn*96 + ni*16 + ln)*128;
      #pragma unroll
      for (int ks=0; ks<2; ks++)
        bfr[ni][ks].q = *reinterpret_cast<const u32x4*>(bufc + rofs + (((ks*4+lg)^lx7)<<4));
    }
    FragU af[2][2];
    #pragma unroll
    for (int mf=0; mf<2; mf++){
      const int rofs = (wm*64 + mf*16 + ln)*128;
      #pragma unroll
      for (int ks=0; ks<2; ks++)
        af[mf][ks].q = *reinterpret_cast<const u32x4*>(bufc + rofs + (((ks*4+lg)^lx7)<<4));
    }
    if (t+1 < nt) stA(cur^1, t+1);
    __builtin_amdgcn_s_barrier();
    __builtin_amdgcn_s_setprio(1);
    #pragma unroll
    for (int ks=0; ks<2; ks++){
      #pragma unroll
      for (int mf=0; mf<2; mf++){
        #pragma unroll
        for (int ni=0; ni<6; ni++)
          acc[mf][ni] = __builtin_amdgcn_mfma_f32_16x16x32_bf16(af[mf][ks].v, bfr[ni][ks].v, acc[mf][ni], 0,0,0);
      }
    }
    __builtin_amdgcn_s_setprio(0);
    asm volatile("s_waitcnt lgkmcnt(0)" ::: "memory");
    __builtin_amdgcn_s_barrier();

    // ---- phase 1: A m-frags 2..3; stage B(t+2) -> B[cur] ----
    FragU ag[2][2];
    #pragma unroll
    for (int mf=0; mf<2; mf++){
      const int rofs = (wm*64 + (mf+2)*16 + ln)*128;
      #pragma unroll
      for (int ks=0; ks<2; ks++)
        ag[mf][ks].q = *reinterpret_cast<const u32x4*>(bufc + rofs + (((ks*4+lg)^lx7)<<4));
    }
    if (t+2 < nt) stB(cur, t+2);
    __builtin_amdgcn_s_barrier();
    __builtin_amdgcn_s_setprio(1);
    #pragma unroll
    for (int ks=0; ks<2; ks++){
      #pragma unroll
      for (int mf=0; mf<2; mf++){
        #pragma unroll
        for (int ni=0; ni<6; ni++)
          acc[mf+2][ni] = __builtin_amdgcn_mfma_f32_16x16x32_bf16(ag[mf][ks].v, bfr[ni][ks].v, acc[mf+2][ni], 0,0,0);
      }
    }
    __builtin_amdgcn_s_setprio(0);
    if (t+1 < nt){
      if (t+2 < nt) asm volatile("s_waitcnt vmcnt(6)" ::: "memory");
      else          asm volatile("s_waitcnt vmcnt(0)" ::: "memory");
    }
    __builtin_amdgcn_s_barrier();
    asm volatile("" ::: "memory");
  }

  #pragma unroll
  for (int mi=0; mi<4; mi++){
    #pragma unroll
    for (int ni=0; ni<6; ni++){
      const int row0 = bm*128 + wm*64 + mi*16 + lg*4;
      const int col  = bn*192 + wn*96 + ni*16 + ln;
      #pragma unroll
      for (int r=0; r<4; r++)
        C[(size_t)(row0+r)*N + col] = acc[mi][ni][r];
    }
  }
}

// ---------------------------------------------------------------------------
// 128x128-tile bf16 GEMM (grid 512 = 2 blocks/CU for M=2048,N=4096).
// ---------------------------------------------------------------------------
__global__ __launch_bounds__(256, 2)
void gemm_pkB2(const u16* __restrict__ A, const u16* __restrict__ B,
               float* __restrict__ C, int M, int N, int K)  // K = bf16 per row
{
  extern __shared__ char smem[];   // 65536 B: [buf2][ A 16KB | B 16KB ]
  const int tid  = threadIdx.x;
  const int lane = tid & 63;
  const int w    = tid >> 6;       // 0..3
  const int wm = w >> 1, wn = w & 1;
  const int ln = lane & 15, lg = lane >> 4;

  const int nbm = M >> 7, nbn = N >> 7;
  const int nwg = nbm * nbn;
  const int swz = (blockIdx.x & 7) * (nwg >> 3) + (blockIdx.x >> 3);
  const int bm = swz % nbm, bn = swz / nbm;

  const size_t rb = (size_t)K * 2;           // row bytes
  const int lrow  = lane >> 3;               // 0..7
  const int lslot = (lane & 7) ^ (lrow & 7); // pre-swizzled source slot
  const char* As0 = (const char*)A + (size_t)(bm*128 + w*8 + lrow)*rb + lslot*16;
  const char* Bs0 = (const char*)B + (size_t)(bn*128 + w*8 + lrow)*rb + lslot*16;

  auto stA = [&](int buf, int t) {           // 4 issues: 128 rows
    const char* s = As0 + ((size_t)t << 7);
    char* d = smem + buf*32768 + w*1024;
    gload16(s,           d);
    gload16(s +  32*rb,  d + 4096);
    gload16(s +  64*rb,  d + 8192);
    gload16(s +  96*rb,  d + 12288);
  };
  auto stB = [&](int buf, int t) {           // 4 issues: 128 rows
    const char* s = Bs0 + ((size_t)t << 7);
    char* d = smem + buf*32768 + 16384 + w*1024;
    gload16(s,           d);
    gload16(s +  32*rb,  d + 4096);
    gload16(s +  64*rb,  d + 8192);
    gload16(s +  96*rb,  d + 12288);
  };

  f32x4 z = {0.f,0.f,0.f,0.f};
  f32x4 acc[4][4];
  #pragma unroll
  for (int i=0;i<4;i++){
    #pragma unroll
    for (int j=0;j<4;j++) acc[i][j] = z;
  }

  const int nt = K >> 6;           // K-tiles of 64 bf16
  stA(0, 0); stB(0, 0);            // 8 loads
  if (nt > 1) { stB(1, 1);         // +4
    asm volatile("s_waitcnt vmcnt(4)" ::: "memory");   // tile0's 8 complete
  } else {
    asm volatile("s_waitcnt vmcnt(0)" ::: "memory");
  }
  __builtin_amdgcn_s_barrier();
  asm volatile("" ::: "memory");

  const int lx7 = ln & 7;

  for (int t = 0; t < nt; ++t){
    const int cur = t & 1;
    const char* bufc = smem + cur*32768;

    // ---- phase 0: all B frags + A m-frags 0..1; stage A(t+1) ----
    FragU bfr[4][2];
    #pragma unroll
    for (int ni=0; ni<4; ni++){
      const int rofs = 16384 + (wn*64 + ni*16 + ln)*128;
      #pragma unroll
      for (int ks=0; ks<2; ks++)
        bfr[ni][ks].q = *reinterpret_cast<const u32x4*>(bufc + rofs + (((ks*4+lg)^lx7)<<4));
    }
    FragU af[2][2];
    #pragma unroll
    for (int mf=0; mf<2; mf++){
      const int rofs = (wm*64 + mf*16 + ln)*128;
      #pragma unroll
      for (int ks=0; ks<2; ks++)
        af[mf][ks].q = *reinterpret_cast<const u32x4*>(bufc + rofs + (((ks*4+lg)^lx7)<<4));
    }
    if (t+1 < nt) stA(cur^1, t+1);
    __builtin_amdgcn_s_barrier();
    __builtin_amdgcn_s_setprio(1);
    #pragma unroll
    for (int ks=0; ks<2; ks++){
      #pragma unroll
      for (int mf=0; mf<2; mf++){
        #pragma unroll
        for (int ni=0; ni<4; ni++)
          acc[mf][ni] = __builtin_amdgcn_mfma_f32_16x16x32_bf16(af[mf][ks].v, bfr[ni][ks].v, acc[mf][ni], 0,0,0);
      }
    }
    __builtin_amdgcn_s_setprio(0);
    asm volatile("s_waitcnt lgkmcnt(0)" ::: "memory");
    __builtin_amdgcn_s_barrier();

    // ---- phase 1: A m-frags 2..3; stage B(t+2) -> B[cur] ----
    FragU ag[2][2];
    #pragma unroll
    for (int mf=0; mf<2; mf++){
      const int rofs = (wm*64 + (mf+2)*16 + ln)*128;
      #pragma unroll
      for (int ks=0; ks<2; ks++)
        ag[mf][ks].q = *reinterpret_cast<const u32x4*>(bufc + rofs + (((ks*4+lg)^lx7)<<4));
    }
    if (t+2 < nt) stB(cur, t+2);
    __builtin_amdgcn_s_barrier();
    __builtin_amdgcn_s_setprio(1);
    #pragma unroll
    for (int ks=0; ks<2; ks++){
      #pragma unroll
      for (int mf=0; mf<2; mf++){
        #pragma unroll
        for (int ni=0; ni<4; ni++)
          acc[mf+2][ni] = __builtin_amdgcn_mfma_f32_16x16x32_bf16(ag[mf][ks].v, bfr[ni][ks].v, acc[mf+2][ni], 0,0,0);
      }
    }
    __builtin_amdgcn_s_setprio(0);
    if (t+1 < nt){
      if (t+2 < nt) asm volatile("s_waitcnt vmcnt(4)" ::: "memory");
      else          asm volatile("s_waitcnt vmcnt(0)" ::: "memory");
    }
    __builtin_amdgcn_s_barrier();
    asm volatile("" ::: "memory");
  }

  #pragma unroll
  for (int mi=0; mi<4; mi++){
    #pragma unroll
    for (int ni=0; ni<4; ni++){
      const int row0 = bm*128 + wm*64 + mi*16 + lg*4;
      const int col  = bn*128 + wn*64 + ni*16 + ln;
      #pragma unroll
      for (int r=0; r<4; r++)
        C[(size_t)(row0+r)*N + col] = acc[mi][ni][r];
    }
  }
}

// ---------------------------------------------------------------------------
// KV-only RMSNorm(K) + partial RoPE(K) + scatter new K/V (both bf16).
// ---------------------------------------------------------------------------
__global__ __launch_bounds__(256)
void norm_rope_kv(const float* __restrict__ qkv, const float* __restrict__ cosT,
                  const float* __restrict__ sinT, const int* __restrict__ positions,
                  const int* __restrict__ cache_seqlens,
                  const float* __restrict__ kw,
                  u16* __restrict__ k_all, u16* __restrict__ v_allT)
{
  const int t = blockIdx.x;
  const int lane = threadIdx.x & 63;
  const int w = threadIdx.x >> 6;
  const int b = t >> 9;        // QL = 512
  const int q = t & 511;
  const int pos  = positions[t];
  const int cpos = cache_seqlens[b] + q;
  for (int it=0; it<4; ++it){
    int hh = it*4 + w;         // 0..15 (0..7 K heads, 8..15 V heads)
    const float* xp = qkv + (size_t)t*6144 + (32+hh)*128 + 2*lane;
    float2 x = *reinterpret_cast<const float2*>(xp);
    if (hh < 8){               // K heads: RMSNorm + RoPE
      float ss = x.x*x.x + x.y*x.y;
      #pragma unroll
      for (int mk=1; mk<64; mk<<=1) ss += __shfl_xor(ss, mk);
      float var = ss*(1.0f/128.0f) + 1e-6f;
      float rq = rsqrtf(var);
      rq = rq*(1.5f - 0.5f*var*rq*rq);   // Newton refine
      x.x *= rq*kw[2*lane]; x.y *= rq*kw[2*lane+1];
      float px = __shfl_xor(x.x, 16);
      float py = __shfl_xor(x.y, 16);
      if (lane < 32){
        int ci = pos*32 + 2*(lane&15);
        float2 cc = *reinterpret_cast<const float2*>(cosT + ci);
        float2 sc = *reinterpret_cast<const float2*>(sinT + ci);
        if (lane < 16){ x.x = x.x*cc.x - px*sc.x; x.y = x.y*cc.y - py*sc.y; }
        else          { x.x = x.x*cc.x + px*sc.x; x.y = x.y*cc.y + py*sc.y; }
      }
      u16* kp = k_all + ((size_t)(b*8 + hh)*1024 + cpos)*128 + 2*lane;
      kp[0] = bfhi(x.x); kp[1] = bfhi(x.y);
    } else {                   // V heads: raw bf16 scatter
      u16* vp = v_allT + ((size_t)(b*8 + (hh-8))*128 + 2*lane)*1024 + cpos;
      vp[0]    = bfhi(x.x);
      vp[1024] = bfhi(x.y);
    }
  }
}

// ---------------------------------------------------------------------------
// Fused GQA causal attention v9: QBLK=128 (8 waves), KVBLK=64, all-bf16,
// Q RMSNorm+RoPE+scale fused into the Q-load (reads RAW q from qkv),
// async dbuf K/V staging (counted vmcnt(4)), no-max softmax, deferred
// l-reduce, bf16 output.  LDS 80KB -> 2 blocks/CU, grid 512.
// ---------------------------------------------------------------------------
__global__ __launch_bounds__(512)
void attn_fused9(const float* __restrict__ qkv, const float* __restrict__ cosT,
                 const float* __restrict__ sinT, const int* __restrict__ positions,
                 const float* __restrict__ qw,
                 const u16* __restrict__ k_all, const u16* __restrict__ v_allT,
                 const int* __restrict__ cache_seqlens, u16* __restrict__ attnO)
{
  extern __shared__ char smem[];          // 80KB: K dbuf 32K | V dbuf 32K | P 16K
  const int tid = threadIdx.x, lane = tid&63, w = tid>>6;   // w 0..7
  const int ln = lane&15, lg = lane>>4;
  const int id = blockIdx.x;
  const int qt = id & 3, g = (id>>2)&3, kvh = (id>>4)&7, b = id>>7;
  const int cs = cache_seqlens[b];
  const int h  = kvh*4 + g;
  const int q0 = qt*128 + w*16;
  const float SCALE = 0.08838834764831845f;  // 1/sqrt(128)
  f32x4 z = {0.f,0.f,0.f,0.f};

  // ---- fused Q: load raw, RMSNorm (4-lane d-split), RoPE, scale, cvt ----
  FragU qf[4];
  {
    const int row = b*512 + q0 + ln;
    const float* qp = qkv + (size_t)row*6144 + h*128;
    float xq[4][8];
    float ss = 0.f;
    #pragma unroll
    for (int ks=0; ks<4; ks++){
      int d0 = ks*32 + lg*8;
      f32x4 a = *reinterpret_cast<const f32x4*>(qp + d0);
      f32x4 c = *reinterpret_cast<const f32x4*>(qp + d0 + 4);
      xq[ks][0]=a.x; xq[ks][1]=a.y; xq[ks][2]=a.z; xq[ks][3]=a.w;
      xq[ks][4]=c.x; xq[ks][5]=c.y; xq[ks][6]=c.z; xq[ks][7]=c.w;
      #pragma unroll
      for (int k2=0;k2<8;k2++) ss += xq[ks][k2]*xq[ks][k2];
    }
    ss += __shfl_xor(ss, 16);
    ss += __shfl_xor(ss, 32);
    float var = ss*(1.0f/128.0f) + 1e-6f;
    float rq = rsqrtf(var);
    rq = rq*(1.5f - 0.5f*var*rq*rq);     // Newton refine (matches norm kernel)
    rq *= SCALE;                          // fold attention scale (rope is linear)
    #pragma unroll
    for (int ks=0; ks<4; ks++){
      int d0 = ks*32 + lg*8;
      f32x4 wa = *reinterpret_cast<const f32x4*>(qw + d0);
      f32x4 wb = *reinterpret_cast<const f32x4*>(qw + d0 + 4);
      xq[ks][0]*=rq*wa.x; xq[ks][1]*=rq*wa.y; xq[ks][2]*=rq*wa.z; xq[ks][3]*=rq*wa.w;
      xq[ks][4]*=rq*wb.x; xq[ks][5]*=rq*wb.y; xq[ks][6]*=rq*wb.z; xq[ks][7]*=rq*wb.w;
    }
    // RoPE on dims 0..63: pair (d, d+32) lives in (ks=0, ks=1) same slot
    const int pos = positions[row];
    const int ci = pos*32 + lg*8;
    #pragma unroll
    for (int k2=0;k2<8;k2+=4){
      f32x4 cc = *reinterpret_cast<const f32x4*>(cosT + ci + k2);
      f32x4 sc = *reinterpret_cast<const f32x4*>(sinT + ci + k2);
      float cA[4] = {cc.x,cc.y,cc.z,cc.w};
      float sA[4] = {sc.x,sc.y,sc.z,sc.w};
      #pragma unroll
      for (int u=0;u<4;u++){
        float x1 = xq[0][k2+u], x2 = xq[1][k2+u];
        xq[0][k2+u] = x1*cA[u] - x2*sA[u];
        xq[1][k2+u] = x2*cA[u] + x1*sA[u];
      }
    }
    #pragma unroll
    for (int ks=0; ks<4; ks++)
      qf[ks].q = (u32x4){ cvtpk(xq[ks][0],xq[ks][1]), cvtpk(xq[ks][2],xq[ks][3]),
                          cvtpk(xq[ks][4],xq[ks][5]), cvtpk(xq[ks][6],xq[ks][7]) };
  }

  f32x4 O[8];
  #pragma unroll
  for (int i=0;i<8;i++) O[i] = z;
  float lacc[4] = {0.f,0.f,0.f,0.f};
  const int prow0 = cs + q0 + lg*4;
  const int nt = (cs + qt*128 + 128 + 63) >> 6;
  const char* kbase = (const char*)(k_all  + (size_t)(b*8+kvh)*1024*128);
  const char* vbase = (const char*)(v_allT + (size_t)(b*8+kvh)*128*1024);

  auto stK = [&](int buf, int t){            // 2 issues: 64 rows x 256B (16KB)
    #pragma unroll
    for (int i=0;i<2;i++){
      int row = i*32 + w*4 + (lane>>4);
      const char* s = kbase + (size_t)(t*64 + row)*256 + (((lane&15) ^ (row&7))<<4);
      gload16(s, smem + buf*16384 + i*8192 + w*1024);
    }
  };
  auto stV = [&](int buf, int t){            // 2 issues: 128 d-rows x 128B (16KB)
    #pragma unroll
    for (int i=0;i<2;i++){
      int row = i*64 + w*8 + (lane>>3);
      const char* s = vbase + (size_t)row*2048 + (size_t)t*128 + (((lane&7) ^ (row&7))<<4);
      gload16(s, smem + 32768 + buf*16384 + i*8192 + w*1024);
    }
  };

  stK(0, 0); stV(0, 0);
  if (nt > 1){ stK(1, 1); stV(1, 1); }

  for (int tile=0; tile<nt; ++tile){
    const int cur = tile & 1;
    const int kv0 = tile*64;
    if (tile+1 < nt) asm volatile("s_waitcnt vmcnt(4)" ::: "memory");
    else             asm volatile("s_waitcnt vmcnt(0)" ::: "memory");
    __builtin_amdgcn_s_barrier();

    // ---- S = Q K^T (bf16, D=128): 4 ks-steps x 4 kv-groups ----
    const u16* Kc = (const u16*)(smem + cur*16384);
    f32x4 s[4]; s[0]=z; s[1]=z; s[2]=z; s[3]=z;
    #pragma unroll
    for (int ks=0; ks<4; ks++){
      int so = ((ks*4+lg) ^ (ln&7)) << 3;
      #pragma unroll
      for (int n=0; n<4; n++){
        FragU kf;
        kf.q = *reinterpret_cast<const u32x4*>(&Kc[(n*16+ln)*128 + so]);
        s[n] = __builtin_amdgcn_mfma_f32_16x16x32_bf16(qf[ks].v, kf.v, s[n], 0,0,0);
      }
    }

    // ---- no-max softmax ----
    float pv[4][4];
    if (kv0 + 63 <= cs + q0){
      #pragma unroll
      for (int n=0;n<4;n++){
        #pragma unroll
        for (int r=0;r<4;r++) pv[n][r] = __expf(s[n][r]);
      }
    } else {
      #pragma unroll
      for (int n=0;n<4;n++){
        #pragma unroll
        for (int r=0;r<4;r++){
          bool ok = (kv0 + n*16 + ln) <= (prow0 + r);
          pv[n][r] = ok ? __expf(s[n][r]) : 0.f;
        }
      }
    }
    #pragma unroll
    for (int r=0;r<4;r++) lacc[r] += (pv[0][r] + pv[1][r]) + (pv[2][r] + pv[3][r]);

    // ---- P -> LDS bf16 [16 q][64 kv] per wave (128B rows, 8-slot swizzle) ----
    #pragma unroll
    for (int n=0;n<4;n++){
      #pragma unroll
      for (int rp=0; rp<2; rp++){
        u32 hpk = cvtpk(pv[n][rp*2], pv[n][rp*2+1]);
        int col  = n*16 + ln;
        int row0 = lg*4 + rp*2;
        int b0 = w*2048 + row0*128 + ((((col>>3) ^ ((row0>>1)&7)))<<4) + (col&7)*2;
        *(u16*)(smem + 65536 + b0)       = (u16)hpk;
        *(u16*)(smem + 65536 + b0 + 128) = (u16)(hpk >> 16);
      }
    }
    FragU pa[2];
    #pragma unroll
    for (int ks2=0; ks2<2; ks2++)
      pa[ks2].q = *reinterpret_cast<const u32x4*>(
          smem + 65536 + w*2048 + ln*128 + (((ks2*4+lg) ^ ((ln>>1)&7))<<4));

    // ---- O += P x V (16 MFMAs) ----
    const char* Vb = smem + 32768 + cur*16384;
    #pragma unroll
    for (int nf=0; nf<8; nf++){
      int dr = nf*16 + ln;
      #pragma unroll
      for (int ks2=0; ks2<2; ks2++){
        FragU vf;
        vf.q = *reinterpret_cast<const u32x4*>(Vb + dr*128 + (((ks2*4+lg) ^ (dr&7))<<4));
        O[nf] = __builtin_amdgcn_mfma_f32_16x16x32_bf16(pa[ks2].v, vf.v, O[nf], 0,0,0);
      }
    }
    asm volatile("s_waitcnt lgkmcnt(0)" ::: "memory");
    __builtin_amdgcn_s_barrier();
    if (tile+2 < nt){ stK(cur, tile+2); stV(cur, tile+2); }
  }

  // deferred row-sum reduce (once)
  #pragma unroll
  for (int off=1; off<16; off<<=1){
    #pragma unroll
    for (int r=0;r<4;r++) lacc[r] += __shfl_xor(lacc[r], off);
  }
  float il[4];
  #pragma unroll
  for (int r=0;r<4;r++) il[r] = 1.0f / lacc[r];
  u16* op = attnO + (size_t)(b*512 + q0 + lg*4)*4096 + h*128 + ln;
  #pragma unroll
  for (int nf=0; nf<8; nf++){
    #pragma unroll
    for (int r=0;r<4;r++)
      op[(size_t)r*4096 + nf*16] = bfhi(O[nf][r] * il[r]);
  }
}

// ---------------------------------------------------------------------------
extern "C" void kernel_launch(void* const* d_in, const int* in_sizes, int n_in,
                              void* d_out, int out_size, void* d_ws, size_t ws_size,
                              hipStream_t stream) {
  const float* hidden    = (const float*)d_in[0];
  const float* cosT      = (const float*)d_in[1];
  const float* sinT      = (const float*)d_in[2];
  const int*   positions = (const int*)  d_in[3];
  const float* k_cache   = (const float*)d_in[4];
  const float* v_cache   = (const float*)d_in[5];
  const int*   page_tab  = (const int*)  d_in[6];
  const int*   cache_sl  = (const int*)  d_in[7];
  const float* qkv_w     = (const float*)d_in[9];
  const float* o_w       = (const float*)d_in[10];
  const float* qnw       = (const float*)d_in[11];
  const float* knw       = (const float*)d_in[12];
  float* out = (float*)d_out;

  float* qkv   = (float*)d_ws;                   // 12582912 f32
  u16* k_all   = (u16*)(qkv + 12582912);         // 4194304 u16
  u16* v_allT  = k_all  + 4194304;               // 4194304 u16
  u16* attnPk  = v_allT + 4194304;               // 8388608 u16
  u16* hidPk   = attnPk + 8388608;               // 8388608 u16
  u16* qkvwPk  = hidPk  + 8388608;               // 25165824 u16
  u16* owPk    = qkvwPk + 25165824;              // 16777216 u16
  (void)in_sizes; (void)n_in; (void)out_size; (void)ws_size;

  (void)hipFuncSetAttribute(reinterpret_cast<const void*>(gemm_pkA2),
                            hipFuncAttributeMaxDynamicSharedMemorySize, 81920);
  (void)hipFuncSetAttribute(reinterpret_cast<const void*>(gemm_pkB2),
                            hipFuncAttributeMaxDynamicSharedMemorySize, 65536);
  (void)hipFuncSetAttribute(reinterpret_cast<const void*>(attn_fused9),
                            hipFuncAttributeMaxDynamicSharedMemorySize, 81920);

  hipLaunchKernelGGL(prep_all, dim3(2560), dim3(256), 0, stream,
                     hidden, (u32*)hidPk, 1048576,
                     qkv_w, (u32*)qkvwPk, 3145728,
                     o_w, (u32*)owPk, 2097152,
                     k_cache, v_cache, page_tab, k_all, v_allT);
  hipLaunchKernelGGL(gemm_pkA2, dim3(512), dim3(256), 81920, stream,
                     hidPk, qkvwPk, qkv, 2048, 6144, 4096);
  hipLaunchKernelGGL(norm_rope_kv, dim3(2048), dim3(256), 0, stream,
                     qkv, cosT, sinT, positions, cache_sl, knw, k_all, v_allT);
  hipLaunchKernelGGL(attn_fused9, dim3(512), dim3(512), 81920, stream,
                     qkv, cosT, sinT, positions, qnw, k_all, v_allT, cache_sl, attnPk);
  hipLaunchKernelGGL(gemm_pkB2, dim3(512), dim3(256), 65536, stream,
                     attnPk, owPk, out, 2048, 4096, 4096);
}

// Round 20
// 294.359 us; speedup vs baseline: 1.0038x; 1.0038x over previous
//
#include <hip/hip_runtime.h>

typedef unsigned int   u32;
typedef unsigned short u16;

typedef float  f32x4  __attribute__((ext_vector_type(4)));
typedef u32    u32x4  __attribute__((ext_vector_type(4)));
typedef u16    u16x4  __attribute__((ext_vector_type(4)));
typedef __bf16 bf16x8 __attribute__((ext_vector_type(8)));

union FragU { u16 us[8]; u32x4 q; bf16x8 v; };

__device__ __forceinline__ u32 f2u(float x){ union{float f;u32 u;}c; c.f=x; return c.u; }
__device__ __forceinline__ float u2f(u32 u){ union{float f;u32 u;}c; c.u=u; return c.f; }
__device__ __forceinline__ u16 bfhi(float x){ u32 u=f2u(x); return (u16)((u + 0x7fffu + ((u>>16)&1u))>>16); }
// pack two fp32 -> (bf16(a) | bf16(b)<<16) via HW cvt (RNE, matches bfhi)
__device__ __forceinline__ u32 cvtpk(float a, float b){
  u32 r;
  asm("v_cvt_pk_bf16_f32 %0, %1, %2" : "=v"(r) : "v"(a), "v"(b));
  return r;
}

__device__ __forceinline__ void gload16(const void* g, void* l){
  __builtin_amdgcn_global_load_lds(
      (const __attribute__((address_space(1))) unsigned int*)g,
      (__attribute__((address_space(3))) unsigned int*)l, 16, 0, 0);
}

// ---------------------------------------------------------------------------
// Pure streaming fp32->bf16 pack, BLOCK-CONTIGUOUS: each block owns 4096
// consecutive 8-float groups (128KB read window).  Segments by block range:
// [0,256) hidden, [256,1024) qkv_w, [1024,1536) o_w -- exact partitions.
// ---------------------------------------------------------------------------
__global__ __launch_bounds__(256)
void prep_pack(const float* __restrict__ s0, u32* __restrict__ d0,
               const float* __restrict__ s1, u32* __restrict__ d1,
               const float* __restrict__ s2, u32* __restrict__ d2)
{
  const int bid = blockIdx.x;
  const float* s; u32* d; int base;
  if (bid < 256)       { s = s0; d = d0; base = bid*4096; }
  else if (bid < 1024) { s = s1; d = d1; base = (bid-256)*4096; }
  else                 { s = s2; d = d2; base = (bid-1024)*4096; }
  int j = base + threadIdx.x;
  #pragma unroll
  for (int it=0; it<8; ++it){          // 2 groups/iter -> 16 groups/thread
    const int j2 = j + 256;
    f32x4 a0 = __builtin_nontemporal_load(reinterpret_cast<const f32x4*>(s) + 2*j);
    f32x4 a1 = __builtin_nontemporal_load(reinterpret_cast<const f32x4*>(s) + 2*j + 1);
    f32x4 b0 = __builtin_nontemporal_load(reinterpret_cast<const f32x4*>(s) + 2*j2);
    f32x4 b1 = __builtin_nontemporal_load(reinterpret_cast<const f32x4*>(s) + 2*j2 + 1);
    reinterpret_cast<u32x4*>(d)[j] =
      (u32x4){ cvtpk(a0.x,a0.y), cvtpk(a0.z,a0.w), cvtpk(a1.x,a1.y), cvtpk(a1.z,a1.w) };
    reinterpret_cast<u32x4*>(d)[j2] =
      (u32x4){ cvtpk(b0.x,b0.y), cvtpk(b0.z,b0.w), cvtpk(b1.x,b1.y), cvtpk(b1.z,b1.w) };
    j += 512;
  }
}

// ---------------------------------------------------------------------------
// 128x192-tile GEMM on bf16 (grid 512 = 2 blocks/CU).
// 4 waves (2Mx2N), wave tile 64x96, BK=64 bf16, dbuf 80KB LDS,
// 2 fat phases/K-tile, counted vmcnt(6), both-sides swizzle, setprio.
// ---------------------------------------------------------------------------
__global__ __launch_bounds__(256, 2)
void gemm_pkA2(const u16* __restrict__ A, const u16* __restrict__ B,
               float* __restrict__ C, int M, int N, int K)  // K = bf16 per row
{
  extern __shared__ char smem[];   // 81920 B: [buf2][ A 16KB | B 24KB ]
  const int tid  = threadIdx.x;
  const int lane = tid & 63;
  const int w    = tid >> 6;       // 0..3
  const int wm = w >> 1, wn = w & 1;
  const int ln = lane & 15, lg = lane >> 4;

  const int nbm = M >> 7;          // 128-row tiles
  const int nbn = N / 192;
  const int nwg = nbm * nbn;
  const int swz = (blockIdx.x & 7) * (nwg >> 3) + (blockIdx.x >> 3);
  const int bm = swz % nbm, bn = swz / nbm;

  const size_t rb = (size_t)K * 2;           // row bytes
  const int lrow  = lane >> 3;               // 0..7
  const int lslot = (lane & 7) ^ (lrow & 7); // pre-swizzled source slot
  const char* As0 = (const char*)A + (size_t)(bm*128 + w*8 + lrow)*rb + lslot*16;
  const char* Bs0 = (const char*)B + (size_t)(bn*192 + w*8 + lrow)*rb + lslot*16;

  auto stA = [&](int buf, int t) {           // 4 issues: 128 rows
    const char* s = As0 + ((size_t)t << 7);
    char* d = smem + buf*40960 + w*1024;
    gload16(s,           d);
    gload16(s +  32*rb,  d + 4096);
    gload16(s +  64*rb,  d + 8192);
    gload16(s +  96*rb,  d + 12288);
  };
  auto stB = [&](int buf, int t) {           // 6 issues: 192 rows
    const char* s = Bs0 + ((size_t)t << 7);
    char* d = smem + buf*40960 + 16384 + w*1024;
    gload16(s,           d);
    gload16(s +  32*rb,  d + 4096);
    gload16(s +  64*rb,  d + 8192);
    gload16(s +  96*rb,  d + 12288);
    gload16(s + 128*rb,  d + 16384);
    gload16(s + 160*rb,  d + 20480);
  };

  f32x4 z = {0.f,0.f,0.f,0.f};
  f32x4 acc[4][6];
  #pragma unroll
  for (int i=0;i<4;i++){
    #pragma unroll
    for (int j=0;j<6;j++) acc[i][j] = z;
  }

  const int nt = K >> 6;           // K-tiles of 64 bf16
  stA(0, 0); stB(0, 0);            // 10 loads
  if (nt > 1) { stB(1, 1);         // +6
    asm volatile("s_waitcnt vmcnt(6)" ::: "memory");   // tile0's 10 complete
  } else {
    asm volatile("s_waitcnt vmcnt(0)" ::: "memory");
  }
  __builtin_amdgcn_s_barrier();
  asm volatile("" ::: "memory");

  const int lx7 = ln & 7;

  for (int t = 0; t < nt; ++t){
    const int cur = t & 1;
    const char* bufc = smem + cur*40960;

    // ---- phase 0: all B frags + A m-frags 0..1; stage A(t+1) ----
    FragU bfr[6][2];
    #pragma unroll
    for (int ni=0; ni<6; ni++){
      const int rofs = 16384 + (wn*96 + ni*16 + ln)*128;
      #pragma unroll
      for (int ks=0; ks<2; ks++)
        bfr[ni][ks].q = *reinterpret_cast<const u32x4*>(bufc + rofs + (((ks*4+lg)^lx7)<<4));
    }
    FragU af[2][2];
    #pragma unroll
    for (int mf=0; mf<2; mf++){
      const int rofs = (wm*64 + mf*16 + ln)*128;
      #pragma unroll
      for (int ks=0; ks<2; ks++)
        af[mf][ks].q = *reinterpret_cast<const u32x4*>(bufc + rofs + (((ks*4+lg)^lx7)<<4));
    }
    if (t+1 < nt) stA(cur^1, t+1);
    __builtin_amdgcn_s_barrier();
    __builtin_amdgcn_s_setprio(1);
    #pragma unroll
    for (int ks=0; ks<2; ks++){
      #pragma unroll
      for (int mf=0; mf<2; mf++){
        #pragma unroll
        for (int ni=0; ni<6; ni++)
          acc[mf][ni] = __builtin_amdgcn_mfma_f32_16x16x32_bf16(af[mf][ks].v, bfr[ni][ks].v, acc[mf][ni], 0,0,0);
      }
    }
    __builtin_amdgcn_s_setprio(0);
    asm volatile("s_waitcnt lgkmcnt(0)" ::: "memory");
    __builtin_amdgcn_s_barrier();

    // ---- phase 1: A m-frags 2..3; stage B(t+2) -> B[cur] ----
    FragU ag[2][2];
    #pragma unroll
    for (int mf=0; mf<2; mf++){
      const int rofs = (wm*64 + (mf+2)*16 + ln)*128;
      #pragma unroll
      for (int ks=0; ks<2; ks++)
        ag[mf][ks].q = *reinterpret_cast<const u32x4*>(bufc + rofs + (((ks*4+lg)^lx7)<<4));
    }
    if (t+2 < nt) stB(cur, t+2);
    __builtin_amdgcn_s_barrier();
    __builtin_amdgcn_s_setprio(1);
    #pragma unroll
    for (int ks=0; ks<2; ks++){
      #pragma unroll
      for (int mf=0; mf<2; mf++){
        #pragma unroll
        for (int ni=0; ni<6; ni++)
          acc[mf+2][ni] = __builtin_amdgcn_mfma_f32_16x16x32_bf16(ag[mf][ks].v, bfr[ni][ks].v, acc[mf+2][ni], 0,0,0);
      }
    }
    __builtin_amdgcn_s_setprio(0);
    if (t+1 < nt){
      if (t+2 < nt) asm volatile("s_waitcnt vmcnt(6)" ::: "memory");
      else          asm volatile("s_waitcnt vmcnt(0)" ::: "memory");
    }
    __builtin_amdgcn_s_barrier();
    asm volatile("" ::: "memory");
  }

  #pragma unroll
  for (int mi=0; mi<4; mi++){
    #pragma unroll
    for (int ni=0; ni<6; ni++){
      const int row0 = bm*128 + wm*64 + mi*16 + lg*4;
      const int col  = bn*192 + wn*96 + ni*16 + ln;
      #pragma unroll
      for (int r=0; r<4; r++)
        C[(size_t)(row0+r)*N + col] = acc[mi][ni][r];
    }
  }
}

// ---------------------------------------------------------------------------
// 128x128-tile bf16 GEMM (grid 512 = 2 blocks/CU for M=2048,N=4096).
// ---------------------------------------------------------------------------
__global__ __launch_bounds__(256, 2)
void gemm_pkB2(const u16* __restrict__ A, const u16* __restrict__ B,
               float* __restrict__ C, int M, int N, int K)  // K = bf16 per row
{
  extern __shared__ char smem[];   // 65536 B: [buf2][ A 16KB | B 16KB ]
  const int tid  = threadIdx.x;
  const int lane = tid & 63;
  const int w    = tid >> 6;       // 0..3
  const int wm = w >> 1, wn = w & 1;
  const int ln = lane & 15, lg = lane >> 4;

  const int nbm = M >> 7, nbn = N >> 7;
  const int nwg = nbm * nbn;
  const int swz = (blockIdx.x & 7) * (nwg >> 3) + (blockIdx.x >> 3);
  const int bm = swz % nbm, bn = swz / nbm;

  const size_t rb = (size_t)K * 2;           // row bytes
  const int lrow  = lane >> 3;               // 0..7
  const int lslot = (lane & 7) ^ (lrow & 7); // pre-swizzled source slot
  const char* As0 = (const char*)A + (size_t)(bm*128 + w*8 + lrow)*rb + lslot*16;
  const char* Bs0 = (const char*)B + (size_t)(bn*128 + w*8 + lrow)*rb + lslot*16;

  auto stA = [&](int buf, int t) {           // 4 issues: 128 rows
    const char* s = As0 + ((size_t)t << 7);
    char* d = smem + buf*32768 + w*1024;
    gload16(s,           d);
    gload16(s +  32*rb,  d + 4096);
    gload16(s +  64*rb,  d + 8192);
    gload16(s +  96*rb,  d + 12288);
  };
  auto stB = [&](int buf, int t) {           // 4 issues: 128 rows
    const char* s = Bs0 + ((size_t)t << 7);
    char* d = smem + buf*32768 + 16384 + w*1024;
    gload16(s,           d);
    gload16(s +  32*rb,  d + 4096);
    gload16(s +  64*rb,  d + 8192);
    gload16(s +  96*rb,  d + 12288);
  };

  f32x4 z = {0.f,0.f,0.f,0.f};
  f32x4 acc[4][4];
  #pragma unroll
  for (int i=0;i<4;i++){
    #pragma unroll
    for (int j=0;j<4;j++) acc[i][j] = z;
  }

  const int nt = K >> 6;           // K-tiles of 64 bf16
  stA(0, 0); stB(0, 0);            // 8 loads
  if (nt > 1) { stB(1, 1);         // +4
    asm volatile("s_waitcnt vmcnt(4)" ::: "memory");   // tile0's 8 complete
  } else {
    asm volatile("s_waitcnt vmcnt(0)" ::: "memory");
  }
  __builtin_amdgcn_s_barrier();
  asm volatile("" ::: "memory");

  const int lx7 = ln & 7;

  for (int t = 0; t < nt; ++t){
    const int cur = t & 1;
    const char* bufc = smem + cur*32768;

    // ---- phase 0: all B frags + A m-frags 0..1; stage A(t+1) ----
    FragU bfr[4][2];
    #pragma unroll
    for (int ni=0; ni<4; ni++){
      const int rofs = 16384 + (wn*64 + ni*16 + ln)*128;
      #pragma unroll
      for (int ks=0; ks<2; ks++)
        bfr[ni][ks].q = *reinterpret_cast<const u32x4*>(bufc + rofs + (((ks*4+lg)^lx7)<<4));
    }
    FragU af[2][2];
    #pragma unroll
    for (int mf=0; mf<2; mf++){
      const int rofs = (wm*64 + mf*16 + ln)*128;
      #pragma unroll
      for (int ks=0; ks<2; ks++)
        af[mf][ks].q = *reinterpret_cast<const u32x4*>(bufc + rofs + (((ks*4+lg)^lx7)<<4));
    }
    if (t+1 < nt) stA(cur^1, t+1);
    __builtin_amdgcn_s_barrier();
    __builtin_amdgcn_s_setprio(1);
    #pragma unroll
    for (int ks=0; ks<2; ks++){
      #pragma unroll
      for (int mf=0; mf<2; mf++){
        #pragma unroll
        for (int ni=0; ni<4; ni++)
          acc[mf][ni] = __builtin_amdgcn_mfma_f32_16x16x32_bf16(af[mf][ks].v, bfr[ni][ks].v, acc[mf][ni], 0,0,0);
      }
    }
    __builtin_amdgcn_s_setprio(0);
    asm volatile("s_waitcnt lgkmcnt(0)" ::: "memory");
    __builtin_amdgcn_s_barrier();

    // ---- phase 1: A m-frags 2..3; stage B(t+2) -> B[cur] ----
    FragU ag[2][2];
    #pragma unroll
    for (int mf=0; mf<2; mf++){
      const int rofs = (wm*64 + (mf+2)*16 + ln)*128;
      #pragma unroll
      for (int ks=0; ks<2; ks++)
        ag[mf][ks].q = *reinterpret_cast<const u32x4*>(bufc + rofs + (((ks*4+lg)^lx7)<<4));
    }
    if (t+2 < nt) stB(cur, t+2);
    __builtin_amdgcn_s_barrier();
    __builtin_amdgcn_s_setprio(1);
    #pragma unroll
    for (int ks=0; ks<2; ks++){
      #pragma unroll
      for (int mf=0; mf<2; mf++){
        #pragma unroll
        for (int ni=0; ni<4; ni++)
          acc[mf+2][ni] = __builtin_amdgcn_mfma_f32_16x16x32_bf16(ag[mf][ks].v, bfr[ni][ks].v, acc[mf+2][ni], 0,0,0);
      }
    }
    __builtin_amdgcn_s_setprio(0);
    if (t+1 < nt){
      if (t+2 < nt) asm volatile("s_waitcnt vmcnt(4)" ::: "memory");
      else          asm volatile("s_waitcnt vmcnt(0)" ::: "memory");
    }
    __builtin_amdgcn_s_barrier();
    asm volatile("" ::: "memory");
  }

  #pragma unroll
  for (int mi=0; mi<4; mi++){
    #pragma unroll
    for (int ni=0; ni<4; ni++){
      const int row0 = bm*128 + wm*64 + mi*16 + lg*4;
      const int col  = bn*128 + wn*64 + ni*16 + ln;
      #pragma unroll
      for (int r=0; r<4; r++)
        C[(size_t)(row0+r)*N + col] = acc[mi][ni][r];
    }
  }
}

// ---------------------------------------------------------------------------
// Fused: KV-heads RMSNorm(K)+RoPE(K)+scatter (blocks 0..2047, writes positions
// >= cs) AND paged cache gather (blocks 2048..3071, writes positions < cs
// ONLY -- disjoint write sets, so block order within the launch is irrelevant).
// ---------------------------------------------------------------------------
__global__ __launch_bounds__(256)
void norm_gather_kv(const float* __restrict__ qkv, const float* __restrict__ cosT,
                    const float* __restrict__ sinT, const int* __restrict__ positions,
                    const int* __restrict__ cache_seqlens,
                    const float* __restrict__ kw,
                    const float* __restrict__ k_cache, const float* __restrict__ v_cache,
                    const int* __restrict__ page_table,
                    u16* __restrict__ k_all, u16* __restrict__ v_allT)
{
  const int tid = threadIdx.x;
  if (blockIdx.x < 2048){
    const int t = blockIdx.x;
    const int lane = tid & 63;
    const int w = tid >> 6;
    const int b = t >> 9;        // QL = 512
    const int q = t & 511;
    const int pos  = positions[t];
    const int cpos = cache_seqlens[b] + q;
    for (int it=0; it<4; ++it){
      int hh = it*4 + w;         // 0..15 (0..7 K heads, 8..15 V heads)
      const float* xp = qkv + (size_t)t*6144 + (32+hh)*128 + 2*lane;
      float2 x = *reinterpret_cast<const float2*>(xp);
      if (hh < 8){               // K heads: RMSNorm + RoPE
        float ss = x.x*x.x + x.y*x.y;
        #pragma unroll
        for (int mk=1; mk<64; mk<<=1) ss += __shfl_xor(ss, mk);
        float var = ss*(1.0f/128.0f) + 1e-6f;
        float rq = rsqrtf(var);
        rq = rq*(1.5f - 0.5f*var*rq*rq);   // Newton refine
        x.x *= rq*kw[2*lane]; x.y *= rq*kw[2*lane+1];
        float px = __shfl_xor(x.x, 16);
        float py = __shfl_xor(x.y, 16);
        if (lane < 32){
          int ci = pos*32 + 2*(lane&15);
          float2 cc = *reinterpret_cast<const float2*>(cosT + ci);
          float2 sc = *reinterpret_cast<const float2*>(sinT + ci);
          if (lane < 16){ x.x = x.x*cc.x - px*sc.x; x.y = x.y*cc.y - py*sc.y; }
          else          { x.x = x.x*cc.x + px*sc.x; x.y = x.y*cc.y + py*sc.y; }
        }
        u16* kp = k_all + ((size_t)(b*8 + hh)*1024 + cpos)*128 + 2*lane;
        kp[0] = bfhi(x.x); kp[1] = bfhi(x.y);
      } else {                   // V heads: raw bf16 scatter
        u16* vp = v_allT + ((size_t)(b*8 + (hh-8))*128 + 2*lane)*1024 + cpos;
        vp[0]    = bfhi(x.x);
        vp[1024] = bfhi(x.y);
      }
    }
    return;
  }
  __shared__ float tb[32][129];
  const int id = blockIdx.x - 2048;
  const int jt = id & 31, h = (id>>5)&7, b = id>>8;
  const int j0 = jt*32;
  const int csb = cache_seqlens[b];
  if (j0 >= csb) return;               // whole block beyond old-cache region
  {
    int r = tid>>3, c = tid&7;           // row 0..31, 8 chunks
    int j = j0 + r;
    int page = page_table[b*64 + (j>>4)];
    int slot = j & 15;
    const float* ks = k_cache + (size_t)((page*16 + slot)*8 + h)*128;
    const float* vs = v_cache + (size_t)((page*16 + slot)*8 + h)*128;
    u16* kd = k_all + ((size_t)(b*8+h)*1024 + j)*128;
    const bool wr = (j < csb);           // gather writes only old positions
    #pragma unroll
    for (int i=0;i<2;i++){
      int d0i = (c + 8*i)*8;             // 8 d-elems per iter
      f32x4 ka = __builtin_nontemporal_load(reinterpret_cast<const f32x4*>(ks + d0i));
      f32x4 kb = __builtin_nontemporal_load(reinterpret_cast<const f32x4*>(ks + d0i + 4));
      if (wr)
        *reinterpret_cast<u32x4*>(kd + d0i) =
          (u32x4){ cvtpk(ka.x,ka.y), cvtpk(ka.z,ka.w), cvtpk(kb.x,kb.y), cvtpk(kb.z,kb.w) };
      f32x4 va = __builtin_nontemporal_load(reinterpret_cast<const f32x4*>(vs + d0i));
      f32x4 vb = __builtin_nontemporal_load(reinterpret_cast<const f32x4*>(vs + d0i + 4));
      tb[r][d0i+0]=va.x; tb[r][d0i+1]=va.y; tb[r][d0i+2]=va.z; tb[r][d0i+3]=va.w;
      tb[r][d0i+4]=vb.x; tb[r][d0i+5]=vb.y; tb[r][d0i+6]=vb.z; tb[r][d0i+7]=vb.w;
    }
  }
  __syncthreads();
  {
    int dout = tid>>1, jh = tid&1;       // d-row 0..127, j-half 0..1
    u16* vd = v_allT + ((size_t)(b*8+h)*128 + dout)*1024 + j0 + jh*16;
    #pragma unroll
    for (int i=0;i<2;i++){
      if (j0 + jh*16 + i*8 < csb){       // 8-col chunk within old region
        int jb = jh*16 + i*8;
        u32x4 o = { cvtpk(tb[jb+0][dout], tb[jb+1][dout]),
                    cvtpk(tb[jb+2][dout], tb[jb+3][dout]),
                    cvtpk(tb[jb+4][dout], tb[jb+5][dout]),
                    cvtpk(tb[jb+6][dout], tb[jb+7][dout]) };
        *reinterpret_cast<u32x4*>(vd + i*8) = o;
      }
    }
  }
}

// ---------------------------------------------------------------------------
// Fused GQA causal attention v9: QBLK=128 (8 waves), KVBLK=64, all-bf16,
// Q RMSNorm+RoPE+scale fused into the Q-load (reads RAW q from qkv),
// async dbuf K/V staging (counted vmcnt(4)), no-max softmax, deferred
// l-reduce, bf16 output.  LDS 80KB -> 2 blocks/CU, grid 512.
// ---------------------------------------------------------------------------
__global__ __launch_bounds__(512)
void attn_fused9(const float* __restrict__ qkv, const float* __restrict__ cosT,
                 const float* __restrict__ sinT, const int* __restrict__ positions,
                 const float* __restrict__ qw,
                 const u16* __restrict__ k_all, const u16* __restrict__ v_allT,
                 const int* __restrict__ cache_seqlens, u16* __restrict__ attnO)
{
  extern __shared__ char smem[];          // 80KB: K dbuf 32K | V dbuf 32K | P 16K
  const int tid = threadIdx.x, lane = tid&63, w = tid>>6;   // w 0..7
  const int ln = lane&15, lg = lane>>4;
  const int id = blockIdx.x;
  const int qt = id & 3, g = (id>>2)&3, kvh = (id>>4)&7, b = id>>7;
  const int cs = cache_seqlens[b];
  const int h  = kvh*4 + g;
  const int q0 = qt*128 + w*16;
  const float SCALE = 0.08838834764831845f;  // 1/sqrt(128)
  f32x4 z = {0.f,0.f,0.f,0.f};

  // ---- fused Q: load raw, RMSNorm (4-lane d-split), RoPE, scale, cvt ----
  FragU qf[4];
  {
    const int row = b*512 + q0 + ln;
    const float* qp = qkv + (size_t)row*6144 + h*128;
    float xq[4][8];
    float ss = 0.f;
    #pragma unroll
    for (int ks=0; ks<4; ks++){
      int d0 = ks*32 + lg*8;
      f32x4 a = *reinterpret_cast<const f32x4*>(qp + d0);
      f32x4 c = *reinterpret_cast<const f32x4*>(qp + d0 + 4);
      xq[ks][0]=a.x; xq[ks][1]=a.y; xq[ks][2]=a.z; xq[ks][3]=a.w;
      xq[ks][4]=c.x; xq[ks][5]=c.y; xq[ks][6]=c.z; xq[ks][7]=c.w;
      #pragma unroll
      for (int k2=0;k2<8;k2++) ss += xq[ks][k2]*xq[ks][k2];
    }
    ss += __shfl_xor(ss, 16);
    ss += __shfl_xor(ss, 32);
    float var = ss*(1.0f/128.0f) + 1e-6f;
    float rq = rsqrtf(var);
    rq = rq*(1.5f - 0.5f*var*rq*rq);     // Newton refine (matches norm kernel)
    rq *= SCALE;                          // fold attention scale (rope is linear)
    #pragma unroll
    for (int ks=0; ks<4; ks++){
      int d0 = ks*32 + lg*8;
      f32x4 wa = *reinterpret_cast<const f32x4*>(qw + d0);
      f32x4 wb = *reinterpret_cast<const f32x4*>(qw + d0 + 4);
      xq[ks][0]*=rq*wa.x; xq[ks][1]*=rq*wa.y; xq[ks][2]*=rq*wa.z; xq[ks][3]*=rq*wa.w;
      xq[ks][4]*=rq*wb.x; xq[ks][5]*=rq*wb.y; xq[ks][6]*=rq*wb.z; xq[ks][7]*=rq*wb.w;
    }
    // RoPE on dims 0..63: pair (d, d+32) lives in (ks=0, ks=1) same slot
    const int pos = positions[row];
    const int ci = pos*32 + lg*8;
    #pragma unroll
    for (int k2=0;k2<8;k2+=4){
      f32x4 cc = *reinterpret_cast<const f32x4*>(cosT + ci + k2);
      f32x4 sc = *reinterpret_cast<const f32x4*>(sinT + ci + k2);
      float cA[4] = {cc.x,cc.y,cc.z,cc.w};
      float sA[4] = {sc.x,sc.y,sc.z,sc.w};
      #pragma unroll
      for (int u=0;u<4;u++){
        float x1 = xq[0][k2+u], x2 = xq[1][k2+u];
        xq[0][k2+u] = x1*cA[u] - x2*sA[u];
        xq[1][k2+u] = x2*cA[u] + x1*sA[u];
      }
    }
    #pragma unroll
    for (int ks=0; ks<4; ks++)
      qf[ks].q = (u32x4){ cvtpk(xq[ks][0],xq[ks][1]), cvtpk(xq[ks][2],xq[ks][3]),
                          cvtpk(xq[ks][4],xq[ks][5]), cvtpk(xq[ks][6],xq[ks][7]) };
  }

  f32x4 O[8];
  #pragma unroll
  for (int i=0;i<8;i++) O[i] = z;
  float lacc[4] = {0.f,0.f,0.f,0.f};
  const int prow0 = cs + q0 + lg*4;
  const int nt = (cs + qt*128 + 128 + 63) >> 6;
  const char* kbase = (const char*)(k_all  + (size_t)(b*8+kvh)*1024*128);
  const char* vbase = (const char*)(v_allT + (size_t)(b*8+kvh)*128*1024);

  auto stK = [&](int buf, int t){            // 2 issues: 64 rows x 256B (16KB)
    #pragma unroll
    for (int i=0;i<2;i++){
      int row = i*32 + w*4 + (lane>>4);
      const char* s = kbase + (size_t)(t*64 + row)*256 + (((lane&15) ^ (row&7))<<4);
      gload16(s, smem + buf*16384 + i*8192 + w*1024);
    }
  };
  auto stV = [&](int buf, int t){            // 2 issues: 128 d-rows x 128B (16KB)
    #pragma unroll
    for (int i=0;i<2;i++){
      int row = i*64 + w*8 + (lane>>3);
      const char* s = vbase + (size_t)row*2048 + (size_t)t*128 + (((lane&7) ^ (row&7))<<4);
      gload16(s, smem + 32768 + buf*16384 + i*8192 + w*1024);
    }
  };

  stK(0, 0); stV(0, 0);
  if (nt > 1){ stK(1, 1); stV(1, 1); }

  for (int tile=0; tile<nt; ++tile){
    const int cur = tile & 1;
    const int kv0 = tile*64;
    if (tile+1 < nt) asm volatile("s_waitcnt vmcnt(4)" ::: "memory");
    else             asm volatile("s_waitcnt vmcnt(0)" ::: "memory");
    __builtin_amdgcn_s_barrier();

    // ---- S = Q K^T (bf16, D=128): 4 ks-steps x 4 kv-groups ----
    const u16* Kc = (const u16*)(smem + cur*16384);
    f32x4 s[4]; s[0]=z; s[1]=z; s[2]=z; s[3]=z;
    #pragma unroll
    for (int ks=0; ks<4; ks++){
      int so = ((ks*4+lg) ^ (ln&7)) << 3;
      #pragma unroll
      for (int n=0; n<4; n++){
        FragU kf;
        kf.q = *reinterpret_cast<const u32x4*>(&Kc[(n*16+ln)*128 + so]);
        s[n] = __builtin_amdgcn_mfma_f32_16x16x32_bf16(qf[ks].v, kf.v, s[n], 0,0,0);
      }
    }

    // ---- no-max softmax ----
    float pv[4][4];
    if (kv0 + 63 <= cs + q0){
      #pragma unroll
      for (int n=0;n<4;n++){
        #pragma unroll
        for (int r=0;r<4;r++) pv[n][r] = __expf(s[n][r]);
      }
    } else {
      #pragma unroll
      for (int n=0;n<4;n++){
        #pragma unroll
        for (int r=0;r<4;r++){
          bool ok = (kv0 + n*16 + ln) <= (prow0 + r);
          pv[n][r] = ok ? __expf(s[n][r]) : 0.f;
        }
      }
    }
    #pragma unroll
    for (int r=0;r<4;r++) lacc[r] += (pv[0][r] + pv[1][r]) + (pv[2][r] + pv[3][r]);

    // ---- P -> LDS bf16 [16 q][64 kv] per wave (128B rows, 8-slot swizzle) ----
    #pragma unroll
    for (int n=0;n<4;n++){
      #pragma unroll
      for (int rp=0; rp<2; rp++){
        u32 hpk = cvtpk(pv[n][rp*2], pv[n][rp*2+1]);
        int col  = n*16 + ln;
        int row0 = lg*4 + rp*2;
        int b0 = w*2048 + row0*128 + ((((col>>3) ^ ((row0>>1)&7)))<<4) + (col&7)*2;
        *(u16*)(smem + 65536 + b0)       = (u16)hpk;
        *(u16*)(smem + 65536 + b0 + 128) = (u16)(hpk >> 16);
      }
    }
    FragU pa[2];
    #pragma unroll
    for (int ks2=0; ks2<2; ks2++)
      pa[ks2].q = *reinterpret_cast<const u32x4*>(
          smem + 65536 + w*2048 + ln*128 + (((ks2*4+lg) ^ ((ln>>1)&7))<<4));

    // ---- O += P x V (16 MFMAs) ----
    const char* Vb = smem + 32768 + cur*16384;
    #pragma unroll
    for (int nf=0; nf<8; nf++){
      int dr = nf*16 + ln;
      #pragma unroll
      for (int ks2=0; ks2<2; ks2++){
        FragU vf;
        vf.q = *reinterpret_cast<const u32x4*>(Vb + dr*128 + (((ks2*4+lg) ^ (dr&7))<<4));
        O[nf] = __builtin_amdgcn_mfma_f32_16x16x32_bf16(pa[ks2].v, vf.v, O[nf], 0,0,0);
      }
    }
    asm volatile("s_waitcnt lgkmcnt(0)" ::: "memory");
    __builtin_amdgcn_s_barrier();
    if (tile+2 < nt){ stK(cur, tile+2); stV(cur, tile+2); }
  }

  // deferred row-sum reduce (once)
  #pragma unroll
  for (int off=1; off<16; off<<=1){
    #pragma unroll
    for (int r=0;r<4;r++) lacc[r] += __shfl_xor(lacc[r], off);
  }
  float il[4];
  #pragma unroll
  for (int r=0;r<4;r++) il[r] = 1.0f / lacc[r];
  u16* op = attnO + (size_t)(b*512 + q0 + lg*4)*4096 + h*128 + ln;
  #pragma unroll
  for (int nf=0; nf<8; nf++){
    #pragma unroll
    for (int r=0;r<4;r++)
      op[(size_t)r*4096 + nf*16] = bfhi(O[nf][r] * il[r]);
  }
}

// ---------------------------------------------------------------------------
extern "C" void kernel_launch(void* const* d_in, const int* in_sizes, int n_in,
                              void* d_out, int out_size, void* d_ws, size_t ws_size,
                              hipStream_t stream) {
  const float* hidden    = (const float*)d_in[0];
  const float* cosT      = (const float*)d_in[1];
  const float* sinT      = (const float*)d_in[2];
  const int*   positions = (const int*)  d_in[3];
  const float* k_cache   = (const float*)d_in[4];
  const float* v_cache   = (const float*)d_in[5];
  const int*   page_tab  = (const int*)  d_in[6];
  const int*   cache_sl  = (const int*)  d_in[7];
  const float* qkv_w     = (const float*)d_in[9];
  const float* o_w       = (const float*)d_in[10];
  const float* qnw       = (const float*)d_in[11];
  const float* knw       = (const float*)d_in[12];
  float* out = (float*)d_out;

  float* qkv   = (float*)d_ws;                   // 12582912 f32
  u16* k_all   = (u16*)(qkv + 12582912);         // 4194304 u16
  u16* v_allT  = k_all  + 4194304;               // 4194304 u16
  u16* attnPk  = v_allT + 4194304;               // 8388608 u16
  u16* hidPk   = attnPk + 8388608;               // 8388608 u16
  u16* qkvwPk  = hidPk  + 8388608;               // 25165824 u16
  u16* owPk    = qkvwPk + 25165824;              // 16777216 u16
  (void)in_sizes; (void)n_in; (void)out_size; (void)ws_size;

  (void)hipFuncSetAttribute(reinterpret_cast<const void*>(gemm_pkA2),
                            hipFuncAttributeMaxDynamicSharedMemorySize, 81920);
  (void)hipFuncSetAttribute(reinterpret_cast<const void*>(gemm_pkB2),
                            hipFuncAttributeMaxDynamicSharedMemorySize, 65536);
  (void)hipFuncSetAttribute(reinterpret_cast<const void*>(attn_fused9),
                            hipFuncAttributeMaxDynamicSharedMemorySize, 81920);

  hipLaunchKernelGGL(prep_pack, dim3(1536), dim3(256), 0, stream,
                     hidden, (u32*)hidPk,
                     qkv_w, (u32*)qkvwPk,
                     o_w, (u32*)owPk);
  hipLaunchKernelGGL(gemm_pkA2, dim3(512), dim3(256), 81920, stream,
                     hidPk, qkvwPk, qkv, 2048, 6144, 4096);
  hipLaunchKernelGGL(norm_gather_kv, dim3(3072), dim3(256), 0, stream,
                     qkv, cosT, sinT, positions, cache_sl, knw,
                     k_cache, v_cache, page_tab, k_all, v_allT);
  hipLaunchKernelGGL(attn_fused9, dim3(512), dim3(512), 81920, stream,
                     qkv, cosT, sinT, positions, qnw, k_all, v_allT, cache_sl, attnPk);
  hipLaunchKernelGGL(gemm_pkB2, dim3(512), dim3(256), 65536, stream,
                     attnPk, owPk, out, 2048, 4096, 4096);
}

// Round 21
// 292.537 us; speedup vs baseline: 1.0101x; 1.0062x over previous
//
#include <hip/hip_runtime.h>

typedef unsigned int   u32;
typedef unsigned short u16;

typedef float  f32x4  __attribute__((ext_vector_type(4)));
typedef u32    u32x4  __attribute__((ext_vector_type(4)));
typedef u16    u16x4  __attribute__((ext_vector_type(4)));
typedef __bf16 bf16x8 __attribute__((ext_vector_type(8)));

union FragU { u16 us[8]; u32x4 q; bf16x8 v; };

__device__ __forceinline__ u32 f2u(float x){ union{float f;u32 u;}c; c.f=x; return c.u; }
__device__ __forceinline__ float u2f(u32 u){ union{float f;u32 u;}c; c.u=u; return c.f; }
__device__ __forceinline__ u16 bfhi(float x){ u32 u=f2u(x); return (u16)((u + 0x7fffu + ((u>>16)&1u))>>16); }
// pack two fp32 -> (bf16(a) | bf16(b)<<16) via HW cvt (RNE, matches bfhi)
__device__ __forceinline__ u32 cvtpk(float a, float b){
  u32 r;
  asm("v_cvt_pk_bf16_f32 %0, %1, %2" : "=v"(r) : "v"(a), "v"(b));
  return r;
}

__device__ __forceinline__ void gload16(const void* g, void* l){
  __builtin_amdgcn_global_load_lds(
      (const __attribute__((address_space(1))) unsigned int*)g,
      (__attribute__((address_space(3))) unsigned int*)l, 16, 0, 0);
}

// ---------------------------------------------------------------------------
// Pure streaming fp32->bf16 pack, BLOCK-CONTIGUOUS: each block owns 4096
// consecutive 8-float groups.  [0,256) hidden, [256,1024) qkv_w, [1024,1536) o_w.
// ---------------------------------------------------------------------------
__global__ __launch_bounds__(256)
void prep_pack(const float* __restrict__ s0, u32* __restrict__ d0,
               const float* __restrict__ s1, u32* __restrict__ d1,
               const float* __restrict__ s2, u32* __restrict__ d2)
{
  const int bid = blockIdx.x;
  const float* s; u32* d; int base;
  if (bid < 256)       { s = s0; d = d0; base = bid*4096; }
  else if (bid < 1024) { s = s1; d = d1; base = (bid-256)*4096; }
  else                 { s = s2; d = d2; base = (bid-1024)*4096; }
  int j = base + threadIdx.x;
  #pragma unroll
  for (int it=0; it<8; ++it){          // 2 groups/iter -> 16 groups/thread
    const int j2 = j + 256;
    f32x4 a0 = __builtin_nontemporal_load(reinterpret_cast<const f32x4*>(s) + 2*j);
    f32x4 a1 = __builtin_nontemporal_load(reinterpret_cast<const f32x4*>(s) + 2*j + 1);
    f32x4 b0 = __builtin_nontemporal_load(reinterpret_cast<const f32x4*>(s) + 2*j2);
    f32x4 b1 = __builtin_nontemporal_load(reinterpret_cast<const f32x4*>(s) + 2*j2 + 1);
    reinterpret_cast<u32x4*>(d)[j] =
      (u32x4){ cvtpk(a0.x,a0.y), cvtpk(a0.z,a0.w), cvtpk(a1.x,a1.y), cvtpk(a1.z,a1.w) };
    reinterpret_cast<u32x4*>(d)[j2] =
      (u32x4){ cvtpk(b0.x,b0.y), cvtpk(b0.z,b0.w), cvtpk(b1.x,b1.y), cvtpk(b1.z,b1.w) };
    j += 512;
  }
}

// ---------------------------------------------------------------------------
// 128x192-tile GEMM on bf16 (grid 512 = 2 blocks/CU), 4 waves (2Mx2N),
// wave tile 64x96, BK=64, dbuf 80KB LDS.  v2: 4 template-shaped phases per
// K-tile -- per phase {ds_read subtile + staged gload_lds slice -> barrier ->
// setprio -> 12 MFMA -> setprio -> barrier}.  Licensing topology and counted
// vmcnt(6) identical to the proven 2-phase version.
// ---------------------------------------------------------------------------
__global__ __launch_bounds__(256, 2)
void gemm_pkA2(const u16* __restrict__ A, const u16* __restrict__ B,
               float* __restrict__ C, int M, int N, int K)  // K = bf16 per row
{
  extern __shared__ char smem[];   // 81920 B: [buf2][ A 16KB | B 24KB ]
  const int tid  = threadIdx.x;
  const int lane = tid & 63;
  const int w    = tid >> 6;       // 0..3
  const int wm = w >> 1, wn = w & 1;
  const int ln = lane & 15, lg = lane >> 4;

  const int nbm = M >> 7;          // 128-row tiles
  const int nbn = N / 192;
  const int nwg = nbm * nbn;
  const int swz = (blockIdx.x & 7) * (nwg >> 3) + (blockIdx.x >> 3);
  const int bm = swz % nbm, bn = swz / nbm;

  const size_t rb = (size_t)K * 2;           // row bytes
  const int lrow  = lane >> 3;               // 0..7
  const int lslot = (lane & 7) ^ (lrow & 7); // pre-swizzled source slot
  const char* As0 = (const char*)A + (size_t)(bm*128 + w*8 + lrow)*rb + lslot*16;
  const char* Bs0 = (const char*)B + (size_t)(bn*192 + w*8 + lrow)*rb + lslot*16;

  auto stA = [&](int buf, int t) {           // 4 issues: 128 rows (prologue)
    const char* s = As0 + ((size_t)t << 7);
    char* d = smem + buf*40960 + w*1024;
    gload16(s,           d);
    gload16(s +  32*rb,  d + 4096);
    gload16(s +  64*rb,  d + 8192);
    gload16(s +  96*rb,  d + 12288);
  };
  auto stB = [&](int buf, int t) {           // 6 issues: 192 rows (prologue)
    const char* s = Bs0 + ((size_t)t << 7);
    char* d = smem + buf*40960 + 16384 + w*1024;
    gload16(s,           d);
    gload16(s +  32*rb,  d + 4096);
    gload16(s +  64*rb,  d + 8192);
    gload16(s +  96*rb,  d + 12288);
    gload16(s + 128*rb,  d + 16384);
    gload16(s + 160*rb,  d + 20480);
  };

  f32x4 z = {0.f,0.f,0.f,0.f};
  f32x4 acc[4][6];
  #pragma unroll
  for (int i=0;i<4;i++){
    #pragma unroll
    for (int j=0;j<6;j++) acc[i][j] = z;
  }

  const int nt = K >> 6;           // K-tiles of 64 bf16
  stA(0, 0); stB(0, 0);            // 10 loads
  if (nt > 1) { stB(1, 1);         // +6
    asm volatile("s_waitcnt vmcnt(6)" ::: "memory");   // tile0's 10 complete
  } else {
    asm volatile("s_waitcnt vmcnt(0)" ::: "memory");
  }
  __builtin_amdgcn_s_barrier();
  asm volatile("" ::: "memory");

  const int lx7 = ln & 7;

  for (int t = 0; t < nt; ++t){
    const int cur = t & 1;
    const char* bufc = smem + cur*40960;
    const bool hasA = (t+1 < nt);
    const bool hasB = (t+2 < nt);
    const char* sA1 = As0 + ((size_t)(t+1) << 7);
    char*       dA1 = smem + (cur^1)*40960 + w*1024;
    const char* sB2 = Bs0 + ((size_t)(t+2) << 7);
    char*       dB2 = smem + cur*40960 + 16384 + w*1024;

    // ---- P1: all B frags + A mf0; stage A(t+1) slices 0-1 ----
    FragU bfr[6][2];
    #pragma unroll
    for (int ni=0; ni<6; ni++){
      const int rofs = 16384 + (wn*96 + ni*16 + ln)*128;
      #pragma unroll
      for (int ks=0; ks<2; ks++)
        bfr[ni][ks].q = *reinterpret_cast<const u32x4*>(bufc + rofs + (((ks*4+lg)^lx7)<<4));
    }
    FragU af[2];
    {
      const int rofs = (wm*64 + ln)*128;
      #pragma unroll
      for (int ks=0; ks<2; ks++)
        af[ks].q = *reinterpret_cast<const u32x4*>(bufc + rofs + (((ks*4+lg)^lx7)<<4));
    }
    if (hasA){ gload16(sA1, dA1); gload16(sA1 + 32*rb, dA1 + 4096); }
    __builtin_amdgcn_s_barrier();
    __builtin_amdgcn_s_setprio(1);
    #pragma unroll
    for (int ks=0; ks<2; ks++){
      #pragma unroll
      for (int ni=0; ni<6; ni++)
        acc[0][ni] = __builtin_amdgcn_mfma_f32_16x16x32_bf16(af[ks].v, bfr[ni][ks].v, acc[0][ni], 0,0,0);
    }
    __builtin_amdgcn_s_setprio(0);
    // fence: all waves' B-frag reads complete before crossing -> licenses
    // stB(t+2) into this buffer's B region from P3 onward.
    asm volatile("s_waitcnt lgkmcnt(0)" ::: "memory");
    __builtin_amdgcn_s_barrier();

    // ---- P2: A mf1; stage A(t+1) slices 2-3 ----
    {
      const int rofs = (wm*64 + 16 + ln)*128;
      #pragma unroll
      for (int ks=0; ks<2; ks++)
        af[ks].q = *reinterpret_cast<const u32x4*>(bufc + rofs + (((ks*4+lg)^lx7)<<4));
    }
    if (hasA){ gload16(sA1 + 64*rb, dA1 + 8192); gload16(sA1 + 96*rb, dA1 + 12288); }
    __builtin_amdgcn_s_barrier();
    __builtin_amdgcn_s_setprio(1);
    #pragma unroll
    for (int ks=0; ks<2; ks++){
      #pragma unroll
      for (int ni=0; ni<6; ni++)
        acc[1][ni] = __builtin_amdgcn_mfma_f32_16x16x32_bf16(af[ks].v, bfr[ni][ks].v, acc[1][ni], 0,0,0);
    }
    __builtin_amdgcn_s_setprio(0);
    __builtin_amdgcn_s_barrier();

    // ---- P3: A mf2; stage B(t+2) slices 0-2 ----
    {
      const int rofs = (wm*64 + 32 + ln)*128;
      #pragma unroll
      for (int ks=0; ks<2; ks++)
        af[ks].q = *reinterpret_cast<const u32x4*>(bufc + rofs + (((ks*4+lg)^lx7)<<4));
    }
    if (hasB){
      gload16(sB2,           dB2);
      gload16(sB2 +  32*rb,  dB2 + 4096);
      gload16(sB2 +  64*rb,  dB2 + 8192);
    }
    __builtin_amdgcn_s_barrier();
    __builtin_amdgcn_s_setprio(1);
    #pragma unroll
    for (int ks=0; ks<2; ks++){
      #pragma unroll
      for (int ni=0; ni<6; ni++)
        acc[2][ni] = __builtin_amdgcn_mfma_f32_16x16x32_bf16(af[ks].v, bfr[ni][ks].v, acc[2][ni], 0,0,0);
    }
    __builtin_amdgcn_s_setprio(0);
    __builtin_amdgcn_s_barrier();

    // ---- P4: A mf3; stage B(t+2) slices 3-5; boundary vmcnt; end-bar ----
    {
      const int rofs = (wm*64 + 48 + ln)*128;
      #pragma unroll
      for (int ks=0; ks<2; ks++)
        af[ks].q = *reinterpret_cast<const u32x4*>(bufc + rofs + (((ks*4+lg)^lx7)<<4));
    }
    if (hasB){
      gload16(sB2 +  96*rb,  dB2 + 12288);
      gload16(sB2 + 128*rb,  dB2 + 16384);
      gload16(sB2 + 160*rb,  dB2 + 20480);
    }
    __builtin_amdgcn_s_barrier();
    __builtin_amdgcn_s_setprio(1);
    #pragma unroll
    for (int ks=0; ks<2; ks++){
      #pragma unroll
      for (int ni=0; ni<6; ni++)
        acc[3][ni] = __builtin_amdgcn_mfma_f32_16x16x32_bf16(af[ks].v, bfr[ni][ks].v, acc[3][ni], 0,0,0);
    }
    __builtin_amdgcn_s_setprio(0);
    // counted wait: leave B(t+2)'s 6 loads in flight; ensure A(t+1)+B(t+1) landed
    if (hasA){
      if (hasB) asm volatile("s_waitcnt vmcnt(6)" ::: "memory");
      else      asm volatile("s_waitcnt vmcnt(0)" ::: "memory");
    }
    __builtin_amdgcn_s_barrier();
    asm volatile("" ::: "memory");
  }

  #pragma unroll
  for (int mi=0; mi<4; mi++){
    #pragma unroll
    for (int ni=0; ni<6; ni++){
      const int row0 = bm*128 + wm*64 + mi*16 + lg*4;
      const int col  = bn*192 + wn*96 + ni*16 + ln;
      #pragma unroll
      for (int r=0; r<4; r++)
        C[(size_t)(row0+r)*N + col] = acc[mi][ni][r];
    }
  }
}

// ---------------------------------------------------------------------------
// 128x128-tile bf16 GEMM (grid 512 = 2 blocks/CU for M=2048,N=4096).
// (unchanged 2-phase control)
// ---------------------------------------------------------------------------
__global__ __launch_bounds__(256, 2)
void gemm_pkB2(const u16* __restrict__ A, const u16* __restrict__ B,
               float* __restrict__ C, int M, int N, int K)  // K = bf16 per row
{
  extern __shared__ char smem[];   // 65536 B: [buf2][ A 16KB | B 16KB ]
  const int tid  = threadIdx.x;
  const int lane = tid & 63;
  const int w    = tid >> 6;       // 0..3
  const int wm = w >> 1, wn = w & 1;
  const int ln = lane & 15, lg = lane >> 4;

  const int nbm = M >> 7, nbn = N >> 7;
  const int nwg = nbm * nbn;
  const int swz = (blockIdx.x & 7) * (nwg >> 3) + (blockIdx.x >> 3);
  const int bm = swz % nbm, bn = swz / nbm;

  const size_t rb = (size_t)K * 2;           // row bytes
  const int lrow  = lane >> 3;               // 0..7
  const int lslot = (lane & 7) ^ (lrow & 7); // pre-swizzled source slot
  const char* As0 = (const char*)A + (size_t)(bm*128 + w*8 + lrow)*rb + lslot*16;
  const char* Bs0 = (const char*)B + (size_t)(bn*128 + w*8 + lrow)*rb + lslot*16;

  auto stA = [&](int buf, int t) {           // 4 issues: 128 rows
    const char* s = As0 + ((size_t)t << 7);
    char* d = smem + buf*32768 + w*1024;
    gload16(s,           d);
    gload16(s +  32*rb,  d + 4096);
    gload16(s +  64*rb,  d + 8192);
    gload16(s +  96*rb,  d + 12288);
  };
  auto stB = [&](int buf, int t) {           // 4 issues: 128 rows
    const char* s = Bs0 + ((size_t)t << 7);
    char* d = smem + buf*32768 + 16384 + w*1024;
    gload16(s,           d);
    gload16(s +  32*rb,  d + 4096);
    gload16(s +  64*rb,  d + 8192);
    gload16(s +  96*rb,  d + 12288);
  };

  f32x4 z = {0.f,0.f,0.f,0.f};
  f32x4 acc[4][4];
  #pragma unroll
  for (int i=0;i<4;i++){
    #pragma unroll
    for (int j=0;j<4;j++) acc[i][j] = z;
  }

  const int nt = K >> 6;           // K-tiles of 64 bf16
  stA(0, 0); stB(0, 0);            // 8 loads
  if (nt > 1) { stB(1, 1);         // +4
    asm volatile("s_waitcnt vmcnt(4)" ::: "memory");   // tile0's 8 complete
  } else {
    asm volatile("s_waitcnt vmcnt(0)" ::: "memory");
  }
  __builtin_amdgcn_s_barrier();
  asm volatile("" ::: "memory");

  const int lx7 = ln & 7;

  for (int t = 0; t < nt; ++t){
    const int cur = t & 1;
    const char* bufc = smem + cur*32768;

    // ---- phase 0: all B frags + A m-frags 0..1; stage A(t+1) ----
    FragU bfr[4][2];
    #pragma unroll
    for (int ni=0; ni<4; ni++){
      const int rofs = 16384 + (wn*64 + ni*16 + ln)*128;
      #pragma unroll
      for (int ks=0; ks<2; ks++)
        bfr[ni][ks].q = *reinterpret_cast<const u32x4*>(bufc + rofs + (((ks*4+lg)^lx7)<<4));
    }
    FragU af[2][2];
    #pragma unroll
    for (int mf=0; mf<2; mf++){
      const int rofs = (wm*64 + mf*16 + ln)*128;
      #pragma unroll
      for (int ks=0; ks<2; ks++)
        af[mf][ks].q = *reinterpret_cast<const u32x4*>(bufc + rofs + (((ks*4+lg)^lx7)<<4));
    }
    if (t+1 < nt) stA(cur^1, t+1);
    __builtin_amdgcn_s_barrier();
    __builtin_amdgcn_s_setprio(1);
    #pragma unroll
    for (int ks=0; ks<2; ks++){
      #pragma unroll
      for (int mf=0; mf<2; mf++){
        #pragma unroll
        for (int ni=0; ni<4; ni++)
          acc[mf][ni] = __builtin_amdgcn_mfma_f32_16x16x32_bf16(af[mf][ks].v, bfr[ni][ks].v, acc[mf][ni], 0,0,0);
      }
    }
    __builtin_amdgcn_s_setprio(0);
    asm volatile("s_waitcnt lgkmcnt(0)" ::: "memory");
    __builtin_amdgcn_s_barrier();

    // ---- phase 1: A m-frags 2..3; stage B(t+2) -> B[cur] ----
    FragU ag[2][2];
    #pragma unroll
    for (int mf=0; mf<2; mf++){
      const int rofs = (wm*64 + (mf+2)*16 + ln)*128;
      #pragma unroll
      for (int ks=0; ks<2; ks++)
        ag[mf][ks].q = *reinterpret_cast<const u32x4*>(bufc + rofs + (((ks*4+lg)^lx7)<<4));
    }
    if (t+2 < nt) stB(cur, t+2);
    __builtin_amdgcn_s_barrier();
    __builtin_amdgcn_s_setprio(1);
    #pragma unroll
    for (int ks=0; ks<2; ks++){
      #pragma unroll
      for (int mf=0; mf<2; mf++){
        #pragma unroll
        for (int ni=0; ni<4; ni++)
          acc[mf+2][ni] = __builtin_amdgcn_mfma_f32_16x16x32_bf16(ag[mf][ks].v, bfr[ni][ks].v, acc[mf+2][ni], 0,0,0);
      }
    }
    __builtin_amdgcn_s_setprio(0);
    if (t+1 < nt){
      if (t+2 < nt) asm volatile("s_waitcnt vmcnt(4)" ::: "memory");
      else          asm volatile("s_waitcnt vmcnt(0)" ::: "memory");
    }
    __builtin_amdgcn_s_barrier();
    asm volatile("" ::: "memory");
  }

  #pragma unroll
  for (int mi=0; mi<4; mi++){
    #pragma unroll
    for (int ni=0; ni<4; ni++){
      const int row0 = bm*128 + wm*64 + mi*16 + lg*4;
      const int col  = bn*128 + wn*64 + ni*16 + ln;
      #pragma unroll
      for (int r=0; r<4; r++)
        C[(size_t)(row0+r)*N + col] = acc[mi][ni][r];
    }
  }
}

// ---------------------------------------------------------------------------
// Fused: KV-heads RMSNorm(K)+RoPE(K)+scatter (blocks 0..2047, writes positions
// >= cs) AND paged cache gather (blocks 2048..3071, writes positions < cs
// ONLY -- disjoint write sets).
// ---------------------------------------------------------------------------
__global__ __launch_bounds__(256)
void norm_gather_kv(const float* __restrict__ qkv, const float* __restrict__ cosT,
                    const float* __restrict__ sinT, const int* __restrict__ positions,
                    const int* __restrict__ cache_seqlens,
                    const float* __restrict__ kw,
                    const float* __restrict__ k_cache, const float* __restrict__ v_cache,
                    const int* __restrict__ page_table,
                    u16* __restrict__ k_all, u16* __restrict__ v_allT)
{
  const int tid = threadIdx.x;
  if (blockIdx.x < 2048){
    const int t = blockIdx.x;
    const int lane = tid & 63;
    const int w = tid >> 6;
    const int b = t >> 9;        // QL = 512
    const int q = t & 511;
    const int pos  = positions[t];
    const int cpos = cache_seqlens[b] + q;
    for (int it=0; it<4; ++it){
      int hh = it*4 + w;         // 0..15 (0..7 K heads, 8..15 V heads)
      const float* xp = qkv + (size_t)t*6144 + (32+hh)*128 + 2*lane;
      float2 x = *reinterpret_cast<const float2*>(xp);
      if (hh < 8){               // K heads: RMSNorm + RoPE
        float ss = x.x*x.x + x.y*x.y;
        #pragma unroll
        for (int mk=1; mk<64; mk<<=1) ss += __shfl_xor(ss, mk);
        float var = ss*(1.0f/128.0f) + 1e-6f;
        float rq = rsqrtf(var);
        rq = rq*(1.5f - 0.5f*var*rq*rq);   // Newton refine
        x.x *= rq*kw[2*lane]; x.y *= rq*kw[2*lane+1];
        float px = __shfl_xor(x.x, 16);
        float py = __shfl_xor(x.y, 16);
        if (lane < 32){
          int ci = pos*32 + 2*(lane&15);
          float2 cc = *reinterpret_cast<const float2*>(cosT + ci);
          float2 sc = *reinterpret_cast<const float2*>(sinT + ci);
          if (lane < 16){ x.x = x.x*cc.x - px*sc.x; x.y = x.y*cc.y - py*sc.y; }
          else          { x.x = x.x*cc.x + px*sc.x; x.y = x.y*cc.y + py*sc.y; }
        }
        u16* kp = k_all + ((size_t)(b*8 + hh)*1024 + cpos)*128 + 2*lane;
        kp[0] = bfhi(x.x); kp[1] = bfhi(x.y);
      } else {                   // V heads: raw bf16 scatter
        u16* vp = v_allT + ((size_t)(b*8 + (hh-8))*128 + 2*lane)*1024 + cpos;
        vp[0]    = bfhi(x.x);
        vp[1024] = bfhi(x.y);
      }
    }
    return;
  }
  __shared__ float tb[32][129];
  const int id = blockIdx.x - 2048;
  const int jt = id & 31, h = (id>>5)&7, b = id>>8;
  const int j0 = jt*32;
  const int csb = cache_seqlens[b];
  if (j0 >= csb) return;               // whole block beyond old-cache region
  {
    int r = tid>>3, c = tid&7;           // row 0..31, 8 chunks
    int j = j0 + r;
    int page = page_table[b*64 + (j>>4)];
    int slot = j & 15;
    const float* ks = k_cache + (size_t)((page*16 + slot)*8 + h)*128;
    const float* vs = v_cache + (size_t)((page*16 + slot)*8 + h)*128;
    u16* kd = k_all + ((size_t)(b*8+h)*1024 + j)*128;
    const bool wr = (j < csb);           // gather writes only old positions
    #pragma unroll
    for (int i=0;i<2;i++){
      int d0i = (c + 8*i)*8;             // 8 d-elems per iter
      f32x4 ka = __builtin_nontemporal_load(reinterpret_cast<const f32x4*>(ks + d0i));
      f32x4 kb = __builtin_nontemporal_load(reinterpret_cast<const f32x4*>(ks + d0i + 4));
      if (wr)
        *reinterpret_cast<u32x4*>(kd + d0i) =
          (u32x4){ cvtpk(ka.x,ka.y), cvtpk(ka.z,ka.w), cvtpk(kb.x,kb.y), cvtpk(kb.z,kb.w) };
      f32x4 va = __builtin_nontemporal_load(reinterpret_cast<const f32x4*>(vs + d0i));
      f32x4 vb = __builtin_nontemporal_load(reinterpret_cast<const f32x4*>(vs + d0i + 4));
      tb[r][d0i+0]=va.x; tb[r][d0i+1]=va.y; tb[r][d0i+2]=va.z; tb[r][d0i+3]=va.w;
      tb[r][d0i+4]=vb.x; tb[r][d0i+5]=vb.y; tb[r][d0i+6]=vb.z; tb[r][d0i+7]=vb.w;
    }
  }
  __syncthreads();
  {
    int dout = tid>>1, jh = tid&1;       // d-row 0..127, j-half 0..1
    u16* vd = v_allT + ((size_t)(b*8+h)*128 + dout)*1024 + j0 + jh*16;
    #pragma unroll
    for (int i=0;i<2;i++){
      if (j0 + jh*16 + i*8 < csb){       // 8-col chunk within old region
        int jb = jh*16 + i*8;
        u32x4 o = { cvtpk(tb[jb+0][dout], tb[jb+1][dout]),
                    cvtpk(tb[jb+2][dout], tb[jb+3][dout]),
                    cvtpk(tb[jb+4][dout], tb[jb+5][dout]),
                    cvtpk(tb[jb+6][dout], tb[jb+7][dout]) };
        *reinterpret_cast<u32x4*>(vd + i*8) = o;
      }
    }
  }
}

// ---------------------------------------------------------------------------
// Fused GQA causal attention v9: QBLK=128 (8 waves), KVBLK=64, all-bf16,
// Q RMSNorm+RoPE+scale fused into the Q-load (reads RAW q from qkv),
// async dbuf K/V staging (counted vmcnt(4)), no-max softmax, deferred
// l-reduce, bf16 output.  LDS 80KB -> 2 blocks/CU, grid 512.
// ---------------------------------------------------------------------------
__global__ __launch_bounds__(512)
void attn_fused9(const float* __restrict__ qkv, const float* __restrict__ cosT,
                 const float* __restrict__ sinT, const int* __restrict__ positions,
                 const float* __restrict__ qw,
                 const u16* __restrict__ k_all, const u16* __restrict__ v_allT,
                 const int* __restrict__ cache_seqlens, u16* __restrict__ attnO)
{
  extern __shared__ char smem[];          // 80KB: K dbuf 32K | V dbuf 32K | P 16K
  const int tid = threadIdx.x, lane = tid&63, w = tid>>6;   // w 0..7
  const int ln = lane&15, lg = lane>>4;
  const int id = blockIdx.x;
  const int qt = id & 3, g = (id>>2)&3, kvh = (id>>4)&7, b = id>>7;
  const int cs = cache_seqlens[b];
  const int h  = kvh*4 + g;
  const int q0 = qt*128 + w*16;
  const float SCALE = 0.08838834764831845f;  // 1/sqrt(128)
  f32x4 z = {0.f,0.f,0.f,0.f};

  // ---- fused Q: load raw, RMSNorm (4-lane d-split), RoPE, scale, cvt ----
  FragU qf[4];
  {
    const int row = b*512 + q0 + ln;
    const float* qp = qkv + (size_t)row*6144 + h*128;
    float xq[4][8];
    float ss = 0.f;
    #pragma unroll
    for (int ks=0; ks<4; ks++){
      int d0 = ks*32 + lg*8;
      f32x4 a = *reinterpret_cast<const f32x4*>(qp + d0);
      f32x4 c = *reinterpret_cast<const f32x4*>(qp + d0 + 4);
      xq[ks][0]=a.x; xq[ks][1]=a.y; xq[ks][2]=a.z; xq[ks][3]=a.w;
      xq[ks][4]=c.x; xq[ks][5]=c.y; xq[ks][6]=c.z; xq[ks][7]=c.w;
      #pragma unroll
      for (int k2=0;k2<8;k2++) ss += xq[ks][k2]*xq[ks][k2];
    }
    ss += __shfl_xor(ss, 16);
    ss += __shfl_xor(ss, 32);
    float var = ss*(1.0f/128.0f) + 1e-6f;
    float rq = rsqrtf(var);
    rq = rq*(1.5f - 0.5f*var*rq*rq);     // Newton refine (matches norm kernel)
    rq *= SCALE;                          // fold attention scale (rope is linear)
    #pragma unroll
    for (int ks=0; ks<4; ks++){
      int d0 = ks*32 + lg*8;
      f32x4 wa = *reinterpret_cast<const f32x4*>(qw + d0);
      f32x4 wb = *reinterpret_cast<const f32x4*>(qw + d0 + 4);
      xq[ks][0]*=rq*wa.x; xq[ks][1]*=rq*wa.y; xq[ks][2]*=rq*wa.z; xq[ks][3]*=rq*wa.w;
      xq[ks][4]*=rq*wb.x; xq[ks][5]*=rq*wb.y; xq[ks][6]*=rq*wb.z; xq[ks][7]*=rq*wb.w;
    }
    // RoPE on dims 0..63: pair (d, d+32) lives in (ks=0, ks=1) same slot
    const int pos = positions[row];
    const int ci = pos*32 + lg*8;
    #pragma unroll
    for (int k2=0;k2<8;k2+=4){
      f32x4 cc = *reinterpret_cast<const f32x4*>(cosT + ci + k2);
      f32x4 sc = *reinterpret_cast<const f32x4*>(sinT + ci + k2);
      float cA[4] = {cc.x,cc.y,cc.z,cc.w};
      float sA[4] = {sc.x,sc.y,sc.z,sc.w};
      #pragma unroll
      for (int u=0;u<4;u++){
        float x1 = xq[0][k2+u], x2 = xq[1][k2+u];
        xq[0][k2+u] = x1*cA[u] - x2*sA[u];
        xq[1][k2+u] = x2*cA[u] + x1*sA[u];
      }
    }
    #pragma unroll
    for (int ks=0; ks<4; ks++)
      qf[ks].q = (u32x4){ cvtpk(xq[ks][0],xq[ks][1]), cvtpk(xq[ks][2],xq[ks][3]),
                          cvtpk(xq[ks][4],xq[ks][5]), cvtpk(xq[ks][6],xq[ks][7]) };
  }

  f32x4 O[8];
  #pragma unroll
  for (int i=0;i<8;i++) O[i] = z;
  float lacc[4] = {0.f,0.f,0.f,0.f};
  const int prow0 = cs + q0 + lg*4;
  const int nt = (cs + qt*128 + 128 + 63) >> 6;
  const char* kbase = (const char*)(k_all  + (size_t)(b*8+kvh)*1024*128);
  const char* vbase = (const char*)(v_allT + (size_t)(b*8+kvh)*128*1024);

  auto stK = [&](int buf, int t){            // 2 issues: 64 rows x 256B (16KB)
    #pragma unroll
    for (int i=0;i<2;i++){
      int row = i*32 + w*4 + (lane>>4);
      const char* s = kbase + (size_t)(t*64 + row)*256 + (((lane&15) ^ (row&7))<<4);
      gload16(s, smem + buf*16384 + i*8192 + w*1024);
    }
  };
  auto stV = [&](int buf, int t){            // 2 issues: 128 d-rows x 128B (16KB)
    #pragma unroll
    for (int i=0;i<2;i++){
      int row = i*64 + w*8 + (lane>>3);
      const char* s = vbase + (size_t)row*2048 + (size_t)t*128 + (((lane&7) ^ (row&7))<<4);
      gload16(s, smem + 32768 + buf*16384 + i*8192 + w*1024);
    }
  };

  stK(0, 0); stV(0, 0);
  if (nt > 1){ stK(1, 1); stV(1, 1); }

  for (int tile=0; tile<nt; ++tile){
    const int cur = tile & 1;
    const int kv0 = tile*64;
    if (tile+1 < nt) asm volatile("s_waitcnt vmcnt(4)" ::: "memory");
    else             asm volatile("s_waitcnt vmcnt(0)" ::: "memory");
    __builtin_amdgcn_s_barrier();

    // ---- S = Q K^T (bf16, D=128): 4 ks-steps x 4 kv-groups ----
    const u16* Kc = (const u16*)(smem + cur*16384);
    f32x4 s[4]; s[0]=z; s[1]=z; s[2]=z; s[3]=z;
    #pragma unroll
    for (int ks=0; ks<4; ks++){
      int so = ((ks*4+lg) ^ (ln&7)) << 3;
      #pragma unroll
      for (int n=0; n<4; n++){
        FragU kf;
        kf.q = *reinterpret_cast<const u32x4*>(&Kc[(n*16+ln)*128 + so]);
        s[n] = __builtin_amdgcn_mfma_f32_16x16x32_bf16(qf[ks].v, kf.v, s[n], 0,0,0);
      }
    }

    // ---- no-max softmax ----
    float pv[4][4];
    if (kv0 + 63 <= cs + q0){
      #pragma unroll
      for (int n=0;n<4;n++){
        #pragma unroll
        for (int r=0;r<4;r++) pv[n][r] = __expf(s[n][r]);
      }
    } else {
      #pragma unroll
      for (int n=0;n<4;n++){
        #pragma unroll
        for (int r=0;r<4;r++){
          bool ok = (kv0 + n*16 + ln) <= (prow0 + r);
          pv[n][r] = ok ? __expf(s[n][r]) : 0.f;
        }
      }
    }
    #pragma unroll
    for (int r=0;r<4;r++) lacc[r] += (pv[0][r] + pv[1][r]) + (pv[2][r] + pv[3][r]);

    // ---- P -> LDS bf16 [16 q][64 kv] per wave (128B rows, 8-slot swizzle) ----
    #pragma unroll
    for (int n=0;n<4;n++){
      #pragma unroll
      for (int rp=0; rp<2; rp++){
        u32 hpk = cvtpk(pv[n][rp*2], pv[n][rp*2+1]);
        int col  = n*16 + ln;
        int row0 = lg*4 + rp*2;
        int b0 = w*2048 + row0*128 + ((((col>>3) ^ ((row0>>1)&7)))<<4) + (col&7)*2;
        *(u16*)(smem + 65536 + b0)       = (u16)hpk;
        *(u16*)(smem + 65536 + b0 + 128) = (u16)(hpk >> 16);
      }
    }
    FragU pa[2];
    #pragma unroll
    for (int ks2=0; ks2<2; ks2++)
      pa[ks2].q = *reinterpret_cast<const u32x4*>(
          smem + 65536 + w*2048 + ln*128 + (((ks2*4+lg) ^ ((ln>>1)&7))<<4));

    // ---- O += P x V (16 MFMAs) ----
    const char* Vb = smem + 32768 + cur*16384;
    #pragma unroll
    for (int nf=0; nf<8; nf++){
      int dr = nf*16 + ln;
      #pragma unroll
      for (int ks2=0; ks2<2; ks2++){
        FragU vf;
        vf.q = *reinterpret_cast<const u32x4*>(Vb + dr*128 + (((ks2*4+lg) ^ (dr&7))<<4));
        O[nf] = __builtin_amdgcn_mfma_f32_16x16x32_bf16(pa[ks2].v, vf.v, O[nf], 0,0,0);
      }
    }
    asm volatile("s_waitcnt lgkmcnt(0)" ::: "memory");
    __builtin_amdgcn_s_barrier();
    if (tile+2 < nt){ stK(cur, tile+2); stV(cur, tile+2); }
  }

  // deferred row-sum reduce (once)
  #pragma unroll
  for (int off=1; off<16; off<<=1){
    #pragma unroll
    for (int r=0;r<4;r++) lacc[r] += __shfl_xor(lacc[r], off);
  }
  float il[4];
  #pragma unroll
  for (int r=0;r<4;r++) il[r] = 1.0f / lacc[r];
  u16* op = attnO + (size_t)(b*512 + q0 + lg*4)*4096 + h*128 + ln;
  #pragma unroll
  for (int nf=0; nf<8; nf++){
    #pragma unroll
    for (int r=0;r<4;r++)
      op[(size_t)r*4096 + nf*16] = bfhi(O[nf][r] * il[r]);
  }
}

// ---------------------------------------------------------------------------
extern "C" void kernel_launch(void* const* d_in, const int* in_sizes, int n_in,
                              void* d_out, int out_size, void* d_ws, size_t ws_size,
                              hipStream_t stream) {
  const float* hidden    = (const float*)d_in[0];
  const float* cosT      = (const float*)d_in[1];
  const float* sinT      = (const float*)d_in[2];
  const int*   positions = (const int*)  d_in[3];
  const float* k_cache   = (const float*)d_in[4];
  const float* v_cache   = (const float*)d_in[5];
  const int*   page_tab  = (const int*)  d_in[6];
  const int*   cache_sl  = (const int*)  d_in[7];
  const float* qkv_w     = (const float*)d_in[9];
  const float* o_w       = (const float*)d_in[10];
  const float* qnw       = (const float*)d_in[11];
  const float* knw       = (const float*)d_in[12];
  float* out = (float*)d_out;

  float* qkv   = (float*)d_ws;                   // 12582912 f32
  u16* k_all   = (u16*)(qkv + 12582912);         // 4194304 u16
  u16* v_allT  = k_all  + 4194304;               // 4194304 u16
  u16* attnPk  = v_allT + 4194304;               // 8388608 u16
  u16* hidPk   = attnPk + 8388608;               // 8388608 u16
  u16* qkvwPk  = hidPk  + 8388608;               // 25165824 u16
  u16* owPk    = qkvwPk + 25165824;              // 16777216 u16
  (void)in_sizes; (void)n_in; (void)out_size; (void)ws_size;

  (void)hipFuncSetAttribute(reinterpret_cast<const void*>(gemm_pkA2),
                            hipFuncAttributeMaxDynamicSharedMemorySize, 81920);
  (void)hipFuncSetAttribute(reinterpret_cast<const void*>(gemm_pkB2),
                            hipFuncAttributeMaxDynamicSharedMemorySize, 65536);
  (void)hipFuncSetAttribute(reinterpret_cast<const void*>(attn_fused9),
                            hipFuncAttributeMaxDynamicSharedMemorySize, 81920);

  hipLaunchKernelGGL(prep_pack, dim3(1536), dim3(256), 0, stream,
                     hidden, (u32*)hidPk,
                     qkv_w, (u32*)qkvwPk,
                     o_w, (u32*)owPk);
  hipLaunchKernelGGL(gemm_pkA2, dim3(512), dim3(256), 81920, stream,
                     hidPk, qkvwPk, qkv, 2048, 6144, 4096);
  hipLaunchKernelGGL(norm_gather_kv, dim3(3072), dim3(256), 0, stream,
                     qkv, cosT, sinT, positions, cache_sl, knw,
                     k_cache, v_cache, page_tab, k_all, v_allT);
  hipLaunchKernelGGL(attn_fused9, dim3(512), dim3(512), 81920, stream,
                     qkv, cosT, sinT, positions, qnw, k_all, v_allT, cache_sl, attnPk);
  hipLaunchKernelGGL(gemm_pkB2, dim3(512), dim3(256), 65536, stream,
                     attnPk, owPk, out, 2048, 4096, 4096);
}